// Round 10
// baseline (72.229 us; speedup 1.0000x reference)
//
#include <hip/hip_runtime.h>
#include <math.h>

#define BDIM 256
#define TP   32                 // output pixels per block (along W)
#define C_   64
#define O_   64
#define H_   128
#define W_   128
#define KK_  9
#define CKK  576
#define HW_  (H_ * W_)          // 16384
#define NE   (TP * KK_)         // 288 gather entries

#define WROWS 7                 // window rows: ho-3 .. ho+3
#define WCOLS 40                // window cols: wo0-3 .. wo0+36
#define WPAD  72                // window col stride in shorts (144 B, bank-safe)
#define WRS   (WCOLS * WPAD)    // 2880 shorts per window row
#define SKKP  72                // sampkk pixel stride in shorts

#define XHWC_OFF     131072     // byte offset of x_hwc (fp32) in ws
typedef short short8 __attribute__((ext_vector_type(8)));
typedef float f32x4  __attribute__((ext_vector_type(4)));

__device__ __forceinline__ unsigned short f2bf(float f) {
    unsigned int u = __float_as_uint(f);
    u += 0x7FFFu + ((u >> 16) & 1u);          // RNE (inputs finite)
    return (unsigned short)(u >> 16);
}

// packed RNE: lo -> bits[15:0], hi -> bits[31:16]
__device__ __forceinline__ unsigned int pk2bf(float lo, float hi) {
    unsigned int r;
    asm("v_cvt_pk_bf16_f32 %0, %1, %2" : "=v"(r) : "v"(lo), "v"(hi));
    return r;
}

__device__ __forceinline__ float bf_lo(unsigned int u) { return __uint_as_float(u << 16); }
__device__ __forceinline__ float bf_hi(unsigned int u) { return __uint_as_float(u & 0xFFFF0000u); }

// ---------------- pre: fused {x NCHW->HWC fp32 transpose} + {weight pack} ----
// (identical to R9's proven kernel)
__global__ __launch_bounds__(BDIM) void dcn_pre(
    const float* __restrict__ x, float* __restrict__ xh,
    const float* __restrict__ w_off, const float* __restrict__ w_mod,
    const float* __restrict__ w_reg, unsigned short* __restrict__ wpack)
{
    __shared__ float tile[32][33];
    if (blockIdx.x >= 4096) {
        int i = (blockIdx.x - 4096) * BDIM + threadIdx.x;
        bool isB = i < 36864;
        int r = isB ? i : i - 36864;
        int j    = r & 7;
        int lane = (r >> 3) & 63;
        int t2   = r >> 9;
        int kstep = t2 % 18;
        int tilei = t2 / 18;
        int k  = kstep * 32 + (lane >> 4) * 8 + j;
        int c  = k & 63;
        int kk = k >> 6;
        int col = tilei * 16 + (lane & 15);
        float v;
        if (isB) {
            v = w_reg[(size_t)col * CKK + c * KK_ + kk];
        } else {
            if (col < 18)      v = w_off[(size_t)col * CKK + c * KK_ + kk];
            else if (col < 27) v = w_mod[(size_t)(col - 18) * CKK + c * KK_ + kk];
            else               v = 0.f;
        }
        wpack[i] = f2bf(v);
        return;
    }
    int wq = blockIdx.x & 3;
    int cq = (blockIdx.x >> 2) & 1;
    int by = blockIdx.x >> 3;
    int b = by >> 7, y = by & 127;
    int w0 = wq * 32, c0 = cq * 32;
    int tw = threadIdx.x & 31, tc = threadIdx.x >> 5;
    const float* xp = x + (size_t)b * C_ * HW_ + (size_t)y * W_;
    #pragma unroll
    for (int k = 0; k < 4; ++k)
        tile[tc + k * 8][tw] = xp[(size_t)(c0 + tc + k * 8) * HW_ + w0 + tw];
    __syncthreads();
    float* op = xh + ((size_t)b * HW_ + (size_t)y * W_) * C_;
    #pragma unroll
    for (int k = 0; k < 4; ++k)
        op[(size_t)(w0 + tc + k * 8) * C_ + c0 + tw] = tile[tw][tc + k * 8];
}

// ------- main fused kernel: LDS window gather + per-kk D/E pipeline (TP=32) -------
__global__ __launch_bounds__(BDIM, 2) void dcn_fused_hwc(
    const float* __restrict__ xh,
    const float* __restrict__ b_off,
    const float* __restrict__ b_mod,
    const unsigned short* __restrict__ wB,
    const unsigned short* __restrict__ wO,
    float* __restrict__ out)
{
    __shared__ __align__(16) unsigned short win[WROWS * WRS];      // 40320 B
    __shared__ __align__(16) unsigned short sampkk[2][TP * SKKP];  // 9216 B
    __shared__ __align__(16) float4 wtab[NE];                      // 4608 B
    __shared__ ushort4        itab[NE];                            // 2304 B
    __shared__ unsigned short fastw[NE];                           // 576 B

    // offs/msk alias sampkk (live only B->C; D writes sampkk after C's barrier)
    float* offs = (float*)&sampkk[0][0];     // 576 floats
    float* msk  = offs + TP * 18;            // 288 floats

    const int t    = threadIdx.x;
    const int wave = t >> 6;
    const int lane = t & 63;
    // XCD-aware swizzle (nwg=2048, %8==0 -> bijective), as R9
    const int blk  = ((blockIdx.x & 7) << 8) | (blockIdx.x >> 3);
    const int wo0  = (blk & 3) * TP;          // 4 tiles per row
    const int ho   = (blk >> 2) & 127;
    const int b    = blk >> 9;

    const float* xb = xh + (size_t)b * HW_ * C_;

    // ---- A: stage bf16 window win[ry][col][c], rows ho-3..ho+3, cols wo0-3..wo0+36
    for (int u = t; u < WROWS * WCOLS * 16; u += BDIM) {
        int rowcol = u >> 4;
        int c4  = (u & 15) * 4;
        int ry  = rowcol / WCOLS;
        int col = rowcol - ry * WCOLS;
        int gy  = ho - 3 + ry;
        int gx  = wo0 - 3 + col;
        float4 v = make_float4(0.f, 0.f, 0.f, 0.f);
        if (gy >= 0 && gy < H_ && gx >= 0 && gx < W_)
            v = *(const float4*)&xb[(size_t)(gy * W_ + gx) * C_ + c4];
        *(uint2*)&win[ry * WRS + col * WPAD + c4] =
            make_uint2(pk2bf(v.x, v.y), pk2bf(v.z, v.w));
    }
    __syncthreads();

    // ---- B: offset(18)+mask(9) conv via MFMA, reading the window directly
    if (wave < 2) {
        f32x4 acc0 = {0.f, 0.f, 0.f, 0.f};
        f32x4 acc1 = {0.f, 0.f, 0.f, 0.f};
        const unsigned short* bp = wO + ((size_t)(wave * 18) * 64 + lane) * 8;
        const int p    = lane & 15;
        const int koff = (lane >> 4) * 8;
        #pragma unroll
        for (int ks = 0; ks < 18; ++ks) {
            const int kk = ks >> 1, ky = kk / 3, kx = kk - ky * 3;
            // pixel p at kernel (ky,kx): window row ky+2, col p+kx+2
            const int ro = (ky + 2) * WRS + (p + kx + 2) * WPAD + koff + (ks & 1) * 32;
            short8 av0 = *(const short8*)&win[ro];
            short8 av1 = *(const short8*)&win[ro + 16 * WPAD];
            short8 bv  = *(const short8*)bp;  bp += 512;
            acc0 = __builtin_amdgcn_mfma_f32_16x16x32_bf16(av0, bv, acc0, 0, 0, 0);
            acc1 = __builtin_amdgcn_mfma_f32_16x16x32_bf16(av1, bv, acc1, 0, 0, 0);
        }
        int oc   = wave * 16 + (lane & 15);
        int prow = (lane >> 4) * 4;
        if (oc < 18) {
            float bias = b_off[oc];
            #pragma unroll
            for (int r = 0; r < 4; ++r) {
                offs[(prow + r) * 18 + oc]      = acc0[r] + bias;
                offs[(prow + 16 + r) * 18 + oc] = acc1[r] + bias;
            }
        } else if (oc < 27) {
            int mc = oc - 18;
            float bias = b_mod[mc];
            #pragma unroll
            for (int r = 0; r < 4; ++r) {
                msk[(prow + r) * KK_ + mc]      = 2.f / (1.f + expf(-(acc0[r] + bias)));
                msk[(prow + 16 + r) * KK_ + mc] = 2.f / (1.f + expf(-(acc1[r] + bias)));
            }
        }
    }
    __syncthreads();

    // ---- C: positions -> folded corner weights + window offset (fast) / global idx (slow)
    for (int e = t; e < NE; e += BDIM) {
        int p  = e / 9;
        int kk = e - p * 9;
        int ky = kk / 3, kx = kk - ky * 3;
        float dy = offs[p * 18 + 2 * kk];
        float dx = offs[p * 18 + 2 * kk + 1];
        float py = dy + (float)(ho - 1 + ky);
        float px = dx + (float)(wo0 + p - 1 + kx);
        float y0f = floorf(py), x0f = floorf(px);
        float wy = py - y0f,    wx = px - x0f;
        int y0 = (int)y0f, x0 = (int)x0f;
        int y1 = y0 + 1,   x1 = x0 + 1;
        float m = msk[p * KK_ + kk];
        float vy0 = (y0 >= 0 && y0 < H_) ? 1.f : 0.f;
        float vy1 = (y1 >= 0 && y1 < H_) ? 1.f : 0.f;
        float vx0 = (x0 >= 0 && x0 < W_) ? 1.f : 0.f;
        float vx1 = (x1 >= 0 && x1 < W_) ? 1.f : 0.f;
        float4 wt;
        wt.x = (1.f - wy) * (1.f - wx) * m * vy0 * vx0;
        wt.y = (1.f - wy) * wx * m * vy0 * vx1;
        wt.z = wy * (1.f - wx) * m * vy1 * vx0;
        wt.w = wy * wx * m * vy1 * vx1;
        wtab[e] = wt;
        // window coords of corner00
        int yr0 = y0 - (ho - 3);
        int xr0 = x0 - (wo0 - 3);
        bool fast = (yr0 >= 0) & (yr0 + 1 < WROWS) & (xr0 >= 0) & (xr0 + 1 < WCOLS);
        fastw[e] = fast ? (unsigned short)((yr0 * WRS + xr0 * WPAD) | 0x8000u) : (unsigned short)0;
        // slow-path clamped global indices (validity already folded into wt)
        int yc0 = min(max(y0, 0), H_ - 1), yc1 = min(max(y1, 0), H_ - 1);
        int xc0 = min(max(x0, 0), W_ - 1), xc1 = min(max(x1, 0), W_ - 1);
        itab[e] = make_ushort4((unsigned short)(yc0 * W_ + xc0),
                               (unsigned short)(yc0 * W_ + xc1),
                               (unsigned short)(yc1 * W_ + xc0),
                               (unsigned short)(yc1 * W_ + xc1));
    }
    __syncthreads();

    // ---- D slice: gather kk for all 32 pixels into sampkk[buf]
    const int c4 = (lane & 15) * 4;
    const int q  = lane >> 4;
    #define DSLICE(kk_, buf_)                                                     \
    {                                                                             \
        _Pragma("unroll")                                                         \
        for (int pass = 0; pass < 2; ++pass) {                                    \
            int p = wave * 8 + pass * 4 + q;                                      \
            int e = p * 9 + (kk_);                                                \
            float4 wt = wtab[e];                                                  \
            unsigned short fw = fastw[e];                                         \
            float s0, s1, s2, s3;                                                 \
            if (fw & 0x8000u) {                                                   \
                int wo = (int)(fw & 0x7FFFu) + c4;                                \
                uint2 a00 = *(const uint2*)&win[wo];                              \
                uint2 a01 = *(const uint2*)&win[wo + WPAD];                       \
                uint2 a10 = *(const uint2*)&win[wo + WRS];                        \
                uint2 a11 = *(const uint2*)&win[wo + WRS + WPAD];                 \
                s0 = bf_lo(a00.x) * wt.x; s1 = bf_hi(a00.x) * wt.x;               \
                s2 = bf_lo(a00.y) * wt.x; s3 = bf_hi(a00.y) * wt.x;               \
                s0 = fmaf(bf_lo(a01.x), wt.y, s0); s1 = fmaf(bf_hi(a01.x), wt.y, s1); \
                s2 = fmaf(bf_lo(a01.y), wt.y, s2); s3 = fmaf(bf_hi(a01.y), wt.y, s3); \
                s0 = fmaf(bf_lo(a10.x), wt.z, s0); s1 = fmaf(bf_hi(a10.x), wt.z, s1); \
                s2 = fmaf(bf_lo(a10.y), wt.z, s2); s3 = fmaf(bf_hi(a10.y), wt.z, s3); \
                s0 = fmaf(bf_lo(a11.x), wt.w, s0); s1 = fmaf(bf_hi(a11.x), wt.w, s1); \
                s2 = fmaf(bf_lo(a11.y), wt.w, s2); s3 = fmaf(bf_hi(a11.y), wt.w, s3); \
            } else {                                                              \
                ushort4 ix = itab[e];                                             \
                const float* basep = xb + c4;                                     \
                float4 v00 = *(const float4*)(basep + ((size_t)ix.x << 6));       \
                float4 v01 = *(const float4*)(basep + ((size_t)ix.y << 6));       \
                float4 v10 = *(const float4*)(basep + ((size_t)ix.z << 6));       \
                float4 v11 = *(const float4*)(basep + ((size_t)ix.w << 6));       \
                s0 = v00.x * wt.x; s1 = v00.y * wt.x; s2 = v00.z * wt.x; s3 = v00.w * wt.x; \
                s0 = fmaf(v01.x, wt.y, s0); s1 = fmaf(v01.y, wt.y, s1);           \
                s2 = fmaf(v01.z, wt.y, s2); s3 = fmaf(v01.w, wt.y, s3);           \
                s0 = fmaf(v10.x, wt.z, s0); s1 = fmaf(v10.y, wt.z, s1);           \
                s2 = fmaf(v10.z, wt.z, s2); s3 = fmaf(v10.w, wt.z, s3);           \
                s0 = fmaf(v11.x, wt.w, s0); s1 = fmaf(v11.y, wt.w, s1);           \
                s2 = fmaf(v11.z, wt.w, s2); s3 = fmaf(v11.w, wt.w, s3);           \
            }                                                                     \
            *(uint2*)&sampkk[buf_][p * SKKP + c4] =                               \
                make_uint2(pk2bf(s0, s1), pk2bf(s2, s3));                         \
        }                                                                         \
    }

    // ---- pipeline: D(kk+1) in flight while E(kk) runs; one barrier per kk
    f32x4 acc0 = {0.f, 0.f, 0.f, 0.f};
    f32x4 acc1 = {0.f, 0.f, 0.f, 0.f};
    const unsigned short* bp = wB + ((size_t)(wave * 18) * 64 + lane) * 8;
    const int arow = (lane & 15) * SKKP + (lane >> 4) * 8;

    DSLICE(0, 0);
    __syncthreads();
    int buf = 0;
    #pragma unroll
    for (int kk = 0; kk < 9; ++kk) {
        if (kk < 8) {
            if (buf) { DSLICE(kk + 1, 0); } else { DSLICE(kk + 1, 1); }
        }
        #pragma unroll
        for (int h = 0; h < 2; ++h) {
            short8 av0 = *(const short8*)&sampkk[buf][arow + h * 32];
            short8 av1 = *(const short8*)&sampkk[buf][arow + 16 * SKKP + h * 32];
            short8 bv  = *(const short8*)bp;  bp += 512;
            acc0 = __builtin_amdgcn_mfma_f32_16x16x32_bf16(av0, bv, acc0, 0, 0, 0);
            acc1 = __builtin_amdgcn_mfma_f32_16x16x32_bf16(av1, bv, acc1, 0, 0, 0);
        }
        __syncthreads();
        buf ^= 1;
    }

    // ---- epilogue: write out
    {
        int o    = wave * 16 + (lane & 15);
        int prow = (lane >> 4) * 4;
        float* ob = out + (size_t)b * O_ * HW_ + (size_t)o * HW_ + ho * W_ + wo0;
        #pragma unroll
        for (int r = 0; r < 4; ++r) {
            ob[prow + r]      = acc0[r];
            ob[16 + prow + r] = acc1[r];
        }
    }
}

extern "C" void kernel_launch(void* const* d_in, const int* in_sizes, int n_in,
                              void* d_out, int out_size, void* d_ws, size_t ws_size,
                              hipStream_t stream) {
    const float* x     = (const float*)d_in[0];
    const float* w_off = (const float*)d_in[1];
    const float* b_off = (const float*)d_in[2];
    const float* w_mod = (const float*)d_in[3];
    const float* b_mod = (const float*)d_in[4];
    const float* w_reg = (const float*)d_in[5];
    float* out = (float*)d_out;

    unsigned short* wpack = (unsigned short*)d_ws;
    float* x_hwc = (float*)((char*)d_ws + XHWC_OFF);

    dcn_pre<<<4096 + 216, BDIM, 0, stream>>>(x, x_hwc, w_off, w_mod, w_reg, wpack);
    dcn_fused_hwc<<<4 * 128 * 4, BDIM, 0, stream>>>(x_hwc, b_off, b_mod,
                                                    wpack, wpack + 36864, out);
}

// Round 11
// 53.956 us; speedup vs baseline: 1.3387x; 1.3387x over previous
//
#include <hip/hip_runtime.h>
#include <math.h>

#define BDIM 256
#define TP   32                 // output pixels per block (along W)
#define C_   64
#define O_   64
#define H_   128
#define W_   128
#define KK_  9
#define CKK  576
#define HW_  (H_ * W_)          // 16384
#define KKS  72                 // padded kk-block stride in shorts (144 B)
#define ROWS (KK_ * KKS)        // 648 shorts per pixel row (1296 B)
#define XTP  72                 // compact x-tile row pad (shorts)
#define XCOLS 34                // compact tile cols (TP + 2 halo)
#define NE   (TP * KK_)         // 288 gather entries

#define XHWC_OFF     131072     // byte offset of x_hwc (fp32) in ws
typedef short short8 __attribute__((ext_vector_type(8)));
typedef float f32x4  __attribute__((ext_vector_type(4)));

__device__ __forceinline__ unsigned short f2bf(float f) {
    unsigned int u = __float_as_uint(f);
    u += 0x7FFFu + ((u >> 16) & 1u);          // RNE (inputs finite)
    return (unsigned short)(u >> 16);
}

// packed RNE: lo -> bits[15:0], hi -> bits[31:16]
__device__ __forceinline__ unsigned int pk2bf(float lo, float hi) {
    unsigned int r;
    asm("v_cvt_pk_bf16_f32 %0, %1, %2" : "=v"(r) : "v"(lo), "v"(hi));
    return r;
}

// ---------------- pre: fused {x NCHW->HWC fp32 transpose} + {weight pack} ----
// wB : [4 tiles][18 ksteps][64 lanes][8]  (w_reg)   36864 shorts @ wpack+0
// wO : [2 tiles][18 ksteps][64 lanes][8]  (w_off/w_mod, cols>=27 zero) @ +36864
// logical K order: k = kk*64 + c ; fragment: k = kstep*32 + (lane>>4)*8 + j
__global__ __launch_bounds__(BDIM) void dcn_pre(
    const float* __restrict__ x, float* __restrict__ xh,
    const float* __restrict__ w_off, const float* __restrict__ w_mod,
    const float* __restrict__ w_reg, unsigned short* __restrict__ wpack)
{
    __shared__ float tile[32][33];
    if (blockIdx.x >= 4096) {
        int i = (blockIdx.x - 4096) * BDIM + threadIdx.x;
        bool isB = i < 36864;
        int r = isB ? i : i - 36864;
        int j    = r & 7;
        int lane = (r >> 3) & 63;
        int t2   = r >> 9;
        int kstep = t2 % 18;
        int tilei = t2 / 18;
        int k  = kstep * 32 + (lane >> 4) * 8 + j;
        int c  = k & 63;
        int kk = k >> 6;
        int col = tilei * 16 + (lane & 15);
        float v;
        if (isB) {
            v = w_reg[(size_t)col * CKK + c * KK_ + kk];
        } else {
            if (col < 18)      v = w_off[(size_t)col * CKK + c * KK_ + kk];
            else if (col < 27) v = w_mod[(size_t)(col - 18) * CKK + c * KK_ + kk];
            else               v = 0.f;
        }
        wpack[i] = f2bf(v);
        return;
    }
    int wq = blockIdx.x & 3;
    int cq = (blockIdx.x >> 2) & 1;
    int by = blockIdx.x >> 3;
    int b = by >> 7, y = by & 127;
    int w0 = wq * 32, c0 = cq * 32;
    int tw = threadIdx.x & 31, tc = threadIdx.x >> 5;
    const float* xp = x + (size_t)b * C_ * HW_ + (size_t)y * W_;
    #pragma unroll
    for (int k = 0; k < 4; ++k)
        tile[tc + k * 8][tw] = xp[(size_t)(c0 + tc + k * 8) * HW_ + w0 + tw];
    __syncthreads();
    float* op = xh + ((size_t)b * HW_ + (size_t)y * W_) * C_;
    #pragma unroll
    for (int k = 0; k < 4; ++k)
        op[(size_t)(w0 + tc + k * 8) * C_ + c0 + tw] = tile[tw][tc + k * 8];
}

// ---------------- main fused kernel (TP=32, reg-resident gather indices) ----------------
__global__ __launch_bounds__(BDIM, 3) void dcn_fused_hwc(
    const float* __restrict__ xh,
    const float* __restrict__ b_off,
    const float* __restrict__ b_mod,
    const unsigned short* __restrict__ wB,
    const unsigned short* __restrict__ wO,
    float* __restrict__ out)
{
    // samp_s also hosts: compact x-tile (102*72 shorts = [0..7344)) during A-B,
    // and offs/msk (floats at short-offset 8192..9920) during B-C.
    __shared__ __align__(16) unsigned short samp_s[TP * ROWS];  // 41472 B
    __shared__ __align__(16) float4 wtab[NE];                   // 4608 B
    __shared__ ushort4        itab[NE];                         // 2304 B
    __shared__ unsigned short dsttab[NE];                       // 576 B

    float* offs = (float*)(samp_s + 8192);   // 576 floats
    float* msk  = offs + TP * 18;            // 288 floats

    const int t    = threadIdx.x;
    const int wave = t >> 6;
    const int lane = t & 63;
    // XCD-aware swizzle (nwg=2048, %8==0 -> bijective): XCD k serves 256
    // consecutive logical tiles = 64 contiguous ho rows (~4.3 MB slice).
    const int blk  = ((blockIdx.x & 7) << 8) | (blockIdx.x >> 3);
    const int wo0  = (blk & 3) * TP;          // 4 tiles per row
    const int ho   = (blk >> 2) & 127;
    const int b    = blk >> 9;

    const float* xb = xh + (size_t)b * HW_ * C_;

    // ---- A: stage compact bf16 tile xt[row=ry*34+col][c], 102 rows x 64 ch
    for (int u = t; u < 102 * 16; u += BDIM) {
        int row = u >> 4;
        int c4  = (u & 15) * 4;
        int ry  = row / XCOLS;
        int col = row - ry * XCOLS;
        int gy  = ho - 1 + ry;
        int gx  = wo0 - 1 + col;
        float4 v = make_float4(0.f, 0.f, 0.f, 0.f);
        if (gy >= 0 && gy < H_ && gx >= 0 && gx < W_)
            v = *(const float4*)&xb[(size_t)(gy * W_ + gx) * C_ + c4];
        *(uint2*)&samp_s[row * XTP + c4] = make_uint2(pk2bf(v.x, v.y), pk2bf(v.z, v.w));
    }
    __syncthreads();

    // ---- B: offset(18)+mask(9) conv via MFMA; 1 bp load feeds 2 pixel halves
    if (wave < 2) {
        f32x4 acc0 = {0.f, 0.f, 0.f, 0.f};
        f32x4 acc1 = {0.f, 0.f, 0.f, 0.f};
        const unsigned short* bp = wO + ((size_t)(wave * 18) * 64 + lane) * 8;
        const unsigned short* ap = samp_s + (lane & 15) * XTP + (lane >> 4) * 8;
        #pragma unroll
        for (int ks = 0; ks < 18; ++ks) {
            const int kk = ks >> 1, ky = kk / 3, kx = kk - ky * 3;
            const int ro = (ky * XCOLS + kx) * XTP + (ks & 1) * 32;
            short8 av0 = *(const short8*)&ap[ro];
            short8 av1 = *(const short8*)&ap[ro + 16 * XTP];
            short8 bv  = *(const short8*)bp;  bp += 512;
            acc0 = __builtin_amdgcn_mfma_f32_16x16x32_bf16(av0, bv, acc0, 0, 0, 0);
            acc1 = __builtin_amdgcn_mfma_f32_16x16x32_bf16(av1, bv, acc1, 0, 0, 0);
        }
        int oc   = wave * 16 + (lane & 15);
        int prow = (lane >> 4) * 4;
        if (oc < 18) {
            float bias = b_off[oc];
            #pragma unroll
            for (int r = 0; r < 4; ++r) {
                offs[(prow + r) * 18 + oc]      = acc0[r] + bias;
                offs[(prow + 16 + r) * 18 + oc] = acc1[r] + bias;
            }
        } else if (oc < 27) {
            int mc = oc - 18;
            float bias = b_mod[mc];
            #pragma unroll
            for (int r = 0; r < 4; ++r) {
                msk[(prow + r) * KK_ + mc]      = 2.f / (1.f + expf(-(acc0[r] + bias)));
                msk[(prow + 16 + r) * KK_ + mc] = 2.f / (1.f + expf(-(acc1[r] + bias)));
            }
        }
    }
    __syncthreads();

    // ---- C: positions -> folded (valid x mask x bilinear) weights + clamped idx
    for (int e = t; e < NE; e += BDIM) {
        int p  = e / 9;
        int kk = e - p * 9;
        int ky = kk / 3, kx = kk - ky * 3;
        float dy = offs[p * 18 + 2 * kk];
        float dx = offs[p * 18 + 2 * kk + 1];
        float py = dy + (float)(ho - 1 + ky);
        float px = dx + (float)(wo0 + p - 1 + kx);
        float y0f = floorf(py), x0f = floorf(px);
        float wy = py - y0f,    wx = px - x0f;
        int y0 = (int)y0f, x0 = (int)x0f;
        int y1 = y0 + 1,   x1 = x0 + 1;
        float m = msk[p * KK_ + kk];
        float vy0 = (y0 >= 0 && y0 < H_) ? 1.f : 0.f;
        float vy1 = (y1 >= 0 && y1 < H_) ? 1.f : 0.f;
        float vx0 = (x0 >= 0 && x0 < W_) ? 1.f : 0.f;
        float vx1 = (x1 >= 0 && x1 < W_) ? 1.f : 0.f;
        float4 wt;
        wt.x = (1.f - wy) * (1.f - wx) * m * vy0 * vx0;
        wt.y = (1.f - wy) * wx * m * vy0 * vx1;
        wt.z = wy * (1.f - wx) * m * vy1 * vx0;
        wt.w = wy * wx * m * vy1 * vx1;
        int yc0 = min(max(y0, 0), H_ - 1), yc1 = min(max(y1, 0), H_ - 1);
        int xc0 = min(max(x0, 0), W_ - 1), xc1 = min(max(x1, 0), W_ - 1);
        wtab[e] = wt;
        itab[e] = make_ushort4((unsigned short)(yc0 * W_ + xc0),
                               (unsigned short)(yc0 * W_ + xc1),
                               (unsigned short)(yc1 * W_ + xc0),
                               (unsigned short)(yc1 * W_ + xc1));
        dsttab[e] = (unsigned short)(p * ROWS + kk * KKS);
    }
    __syncthreads();

    // ---- D: bilinear gather, 4 ch/lane; indices preloaded to registers so the
    //      address chain has NO per-iteration LDS dependency; depth-2 prefetch.
    {
        const int c4 = (lane & 15) * 4;
        const int q  = lane >> 4;
        const float* base = xb + c4;

        // preload this lane's 18 corner-index quads (statically indexed -> regs)
        ushort4 ixr[18];
        #pragma unroll
        for (int it = 0; it < 18; ++it)
            ixr[it] = itab[wave * 72 + it * 4 + q];

        #define ISSUE(itv, d00, d01, d10, d11)                       \
            { ushort4 ix_ = ixr[itv];                                \
              d00 = *(const float4*)(base + ((size_t)ix_.x << 6));   \
              d01 = *(const float4*)(base + ((size_t)ix_.y << 6));   \
              d10 = *(const float4*)(base + ((size_t)ix_.z << 6));   \
              d11 = *(const float4*)(base + ((size_t)ix_.w << 6)); }

        float4 p00, p01, p10, p11;
        ISSUE(0, p00, p01, p10, p11);
        #pragma unroll
        for (int it = 0; it < 18; ++it) {
            float4 n00, n01, n10, n11;
            if (it < 17) ISSUE(it + 1, n00, n01, n10, n11);
            const int e = wave * 72 + it * 4 + q;
            float4 wt  = wtab[e];
            int    dst = dsttab[e];
            float s0 = p00.x * wt.x;
            s0 = fmaf(p01.x, wt.y, s0); s0 = fmaf(p10.x, wt.z, s0); s0 = fmaf(p11.x, wt.w, s0);
            float s1 = p00.y * wt.x;
            s1 = fmaf(p01.y, wt.y, s1); s1 = fmaf(p10.y, wt.z, s1); s1 = fmaf(p11.y, wt.w, s1);
            float s2 = p00.z * wt.x;
            s2 = fmaf(p01.z, wt.y, s2); s2 = fmaf(p10.z, wt.z, s2); s2 = fmaf(p11.z, wt.w, s2);
            float s3 = p00.w * wt.x;
            s3 = fmaf(p01.w, wt.y, s3); s3 = fmaf(p10.w, wt.z, s3); s3 = fmaf(p11.w, wt.w, s3);
            *(uint2*)&samp_s[dst + c4] = make_uint2(pk2bf(s0, s1), pk2bf(s2, s3));
            if (it < 17) { p00 = n00; p01 = n01; p10 = n10; p11 = n11; }
        }
        #undef ISSUE
    }
    __syncthreads();

    // ---- E: out[p][o] via MFMA; 1 bp load feeds 2 pixel halves
    {
        f32x4 acc0 = {0.f, 0.f, 0.f, 0.f};
        f32x4 acc1 = {0.f, 0.f, 0.f, 0.f};
        const unsigned short* bp = wB + ((size_t)(wave * 18) * 64 + lane) * 8;
        const int arow = (lane & 15) * ROWS + (lane >> 4) * 8;
        #pragma unroll
        for (int ks = 0; ks < 18; ++ks) {
            const int ro = arow + (ks >> 1) * KKS + (ks & 1) * 32;
            short8 av0 = *(const short8*)&samp_s[ro];
            short8 av1 = *(const short8*)&samp_s[ro + 16 * ROWS];
            short8 bv  = *(const short8*)bp;  bp += 512;
            acc0 = __builtin_amdgcn_mfma_f32_16x16x32_bf16(av0, bv, acc0, 0, 0, 0);
            acc1 = __builtin_amdgcn_mfma_f32_16x16x32_bf16(av1, bv, acc1, 0, 0, 0);
        }
        int o    = wave * 16 + (lane & 15);
        int prow = (lane >> 4) * 4;
        float* ob = out + (size_t)b * O_ * HW_ + (size_t)o * HW_ + ho * W_ + wo0;
        #pragma unroll
        for (int r = 0; r < 4; ++r) {
            ob[prow + r]      = acc0[r];
            ob[16 + prow + r] = acc1[r];
        }
    }
}

extern "C" void kernel_launch(void* const* d_in, const int* in_sizes, int n_in,
                              void* d_out, int out_size, void* d_ws, size_t ws_size,
                              hipStream_t stream) {
    const float* x     = (const float*)d_in[0];
    const float* w_off = (const float*)d_in[1];
    const float* b_off = (const float*)d_in[2];
    const float* w_mod = (const float*)d_in[3];
    const float* b_mod = (const float*)d_in[4];
    const float* w_reg = (const float*)d_in[5];
    float* out = (float*)d_out;

    unsigned short* wpack = (unsigned short*)d_ws;
    float* x_hwc = (float*)((char*)d_ws + XHWC_OFF);

    dcn_pre<<<4096 + 216, BDIM, 0, stream>>>(x, x_hwc, w_off, w_mod, w_reg, wpack);
    dcn_fused_hwc<<<4 * 128 * 4, BDIM, 0, stream>>>(x_hwc, b_off, b_mod,
                                                    wpack, wpack + 36864, out);
}

// Round 12
// 53.067 us; speedup vs baseline: 1.3611x; 1.0167x over previous
//
#include <hip/hip_runtime.h>
#include <math.h>

#define BDIM 256
#define TP   32                 // output pixels per block (along W)
#define C_   64
#define O_   64
#define H_   128
#define W_   128
#define KK_  9
#define CKK  576
#define HW_  (H_ * W_)          // 16384
#define KKS  72                 // padded kk-block stride in shorts (144 B)
#define ROWS (KK_ * KKS)        // 648 shorts per pixel row (1296 B)
#define XTP  72                 // compact x-tile row pad (shorts)
#define XCOLS 34                // compact tile cols (TP + 2 halo)
#define NE   (TP * KK_)         // 288 gather entries
#define NBLK 2048

// ---- ws layout (split path) ----
#define WTAB_OFF  131072
#define ITAB_OFF  (WTAB_OFF + (size_t)NBLK * NE * 16)   //  9,568,256
#define XHWC2_OFF (ITAB_OFF + (size_t)NBLK * NE * 8)    // 14,286,848
#define WS_SPLIT  (XHWC2_OFF + (size_t)4 * HW_ * C_ * 4)// 31,064,064
// ---- ws layout (fallback monolithic path) ----
#define XHWC_OFF  131072

typedef short short8 __attribute__((ext_vector_type(8)));
typedef float f32x4  __attribute__((ext_vector_type(4)));

__device__ __forceinline__ unsigned short f2bf(float f) {
    unsigned int u = __float_as_uint(f);
    u += 0x7FFFu + ((u >> 16) & 1u);          // RNE (inputs finite)
    return (unsigned short)(u >> 16);
}

// packed RNE: lo -> bits[15:0], hi -> bits[31:16]
__device__ __forceinline__ unsigned int pk2bf(float lo, float hi) {
    unsigned int r;
    asm("v_cvt_pk_bf16_f32 %0, %1, %2" : "=v"(r) : "v"(lo), "v"(hi));
    return r;
}

// ---------------- pre: fused {x NCHW->HWC fp32 transpose} + {weight pack} ----
__global__ __launch_bounds__(BDIM) void dcn_pre(
    const float* __restrict__ x, float* __restrict__ xh,
    const float* __restrict__ w_off, const float* __restrict__ w_mod,
    const float* __restrict__ w_reg, unsigned short* __restrict__ wpack)
{
    __shared__ float tile[32][33];
    if (blockIdx.x >= 4096) {
        int i = (blockIdx.x - 4096) * BDIM + threadIdx.x;
        bool isB = i < 36864;
        int r = isB ? i : i - 36864;
        int j    = r & 7;
        int lane = (r >> 3) & 63;
        int t2   = r >> 9;
        int kstep = t2 % 18;
        int tilei = t2 / 18;
        int k  = kstep * 32 + (lane >> 4) * 8 + j;
        int c  = k & 63;
        int kk = k >> 6;
        int col = tilei * 16 + (lane & 15);
        float v;
        if (isB) {
            v = w_reg[(size_t)col * CKK + c * KK_ + kk];
        } else {
            if (col < 18)      v = w_off[(size_t)col * CKK + c * KK_ + kk];
            else if (col < 27) v = w_mod[(size_t)(col - 18) * CKK + c * KK_ + kk];
            else               v = 0.f;
        }
        wpack[i] = f2bf(v);
        return;
    }
    int wq = blockIdx.x & 3;
    int cq = (blockIdx.x >> 2) & 1;
    int by = blockIdx.x >> 3;
    int b = by >> 7, y = by & 127;
    int w0 = wq * 32, c0 = cq * 32;
    int tw = threadIdx.x & 31, tc = threadIdx.x >> 5;
    const float* xp = x + (size_t)b * C_ * HW_ + (size_t)y * W_;
    #pragma unroll
    for (int k = 0; k < 4; ++k)
        tile[tc + k * 8][tw] = xp[(size_t)(c0 + tc + k * 8) * HW_ + w0 + tw];
    __syncthreads();
    float* op = xh + ((size_t)b * HW_ + (size_t)y * W_) * C_;
    #pragma unroll
    for (int k = 0; k < 4; ++k)
        op[(size_t)(w0 + tc + k * 8) * C_ + c0 + tw] = tile[tw][tc + k * 8];
}

// ---- shared device helper: A(stage xtile) + B(offset/mask MFMA) + C(fold) ----
// Writes wt/ix per entry via the provided sinks. Used by tabs and mono kernels.

// ---------------- kernel 1: tabs = A + B + C, outputs wtab_g/itab_g ----------------
__global__ __launch_bounds__(BDIM, 4) void dcn_tabs(
    const float* __restrict__ xh,
    const float* __restrict__ b_off,
    const float* __restrict__ b_mod,
    const unsigned short* __restrict__ wO,
    float4* __restrict__ wtab_g,
    ushort4* __restrict__ itab_g)
{
    __shared__ __align__(16) unsigned short xtile[102 * XTP];   // 14688 B
    __shared__ float offs[TP * 18];                             // 2304 B
    __shared__ float msk [TP * KK_];                            // 1152 B

    const int t    = threadIdx.x;
    const int wave = t >> 6;
    const int lane = t & 63;
    const int blk  = ((blockIdx.x & 7) << 8) | (blockIdx.x >> 3);   // XCD swizzle
    const int wo0  = (blk & 3) * TP;
    const int ho   = (blk >> 2) & 127;
    const int b    = blk >> 9;

    const float* xb = xh + (size_t)b * HW_ * C_;

    // ---- A
    for (int u = t; u < 102 * 16; u += BDIM) {
        int row = u >> 4;
        int c4  = (u & 15) * 4;
        int ry  = row / XCOLS;
        int col = row - ry * XCOLS;
        int gy  = ho - 1 + ry;
        int gx  = wo0 - 1 + col;
        float4 v = make_float4(0.f, 0.f, 0.f, 0.f);
        if (gy >= 0 && gy < H_ && gx >= 0 && gx < W_)
            v = *(const float4*)&xb[(size_t)(gy * W_ + gx) * C_ + c4];
        *(uint2*)&xtile[row * XTP + c4] = make_uint2(pk2bf(v.x, v.y), pk2bf(v.z, v.w));
    }
    __syncthreads();

    // ---- B
    if (wave < 2) {
        f32x4 acc0 = {0.f, 0.f, 0.f, 0.f};
        f32x4 acc1 = {0.f, 0.f, 0.f, 0.f};
        const unsigned short* bp = wO + ((size_t)(wave * 18) * 64 + lane) * 8;
        const unsigned short* ap = xtile + (lane & 15) * XTP + (lane >> 4) * 8;
        #pragma unroll
        for (int ks = 0; ks < 18; ++ks) {
            const int kk = ks >> 1, ky = kk / 3, kx = kk - ky * 3;
            const int ro = (ky * XCOLS + kx) * XTP + (ks & 1) * 32;
            short8 av0 = *(const short8*)&ap[ro];
            short8 av1 = *(const short8*)&ap[ro + 16 * XTP];
            short8 bv  = *(const short8*)bp;  bp += 512;
            acc0 = __builtin_amdgcn_mfma_f32_16x16x32_bf16(av0, bv, acc0, 0, 0, 0);
            acc1 = __builtin_amdgcn_mfma_f32_16x16x32_bf16(av1, bv, acc1, 0, 0, 0);
        }
        int oc   = wave * 16 + (lane & 15);
        int prow = (lane >> 4) * 4;
        if (oc < 18) {
            float bias = b_off[oc];
            #pragma unroll
            for (int r = 0; r < 4; ++r) {
                offs[(prow + r) * 18 + oc]      = acc0[r] + bias;
                offs[(prow + 16 + r) * 18 + oc] = acc1[r] + bias;
            }
        } else if (oc < 27) {
            int mc = oc - 18;
            float bias = b_mod[mc];
            #pragma unroll
            for (int r = 0; r < 4; ++r) {
                msk[(prow + r) * KK_ + mc]      = 2.f / (1.f + expf(-(acc0[r] + bias)));
                msk[(prow + 16 + r) * KK_ + mc] = 2.f / (1.f + expf(-(acc1[r] + bias)));
            }
        }
    }
    __syncthreads();

    // ---- C -> global tabs (ordered by logical block)
    float4*  wg = wtab_g + (size_t)blk * NE;
    ushort4* ig = itab_g + (size_t)blk * NE;
    for (int e = t; e < NE; e += BDIM) {
        int p  = e / 9;
        int kk = e - p * 9;
        int ky = kk / 3, kx = kk - ky * 3;
        float dy = offs[p * 18 + 2 * kk];
        float dx = offs[p * 18 + 2 * kk + 1];
        float py = dy + (float)(ho - 1 + ky);
        float px = dx + (float)(wo0 + p - 1 + kx);
        float y0f = floorf(py), x0f = floorf(px);
        float wy = py - y0f,    wx = px - x0f;
        int y0 = (int)y0f, x0 = (int)x0f;
        int y1 = y0 + 1,   x1 = x0 + 1;
        float m = msk[p * KK_ + kk];
        float vy0 = (y0 >= 0 && y0 < H_) ? 1.f : 0.f;
        float vy1 = (y1 >= 0 && y1 < H_) ? 1.f : 0.f;
        float vx0 = (x0 >= 0 && x0 < W_) ? 1.f : 0.f;
        float vx1 = (x1 >= 0 && x1 < W_) ? 1.f : 0.f;
        float4 wt;
        wt.x = (1.f - wy) * (1.f - wx) * m * vy0 * vx0;
        wt.y = (1.f - wy) * wx * m * vy0 * vx1;
        wt.z = wy * (1.f - wx) * m * vy1 * vx0;
        wt.w = wy * wx * m * vy1 * vx1;
        int yc0 = min(max(y0, 0), H_ - 1), yc1 = min(max(y1, 0), H_ - 1);
        int xc0 = min(max(x0, 0), W_ - 1), xc1 = min(max(x1, 0), W_ - 1);
        wg[e] = wt;
        ig[e] = make_ushort4((unsigned short)(yc0 * W_ + xc0),
                             (unsigned short)(yc0 * W_ + xc1),
                             (unsigned short)(yc1 * W_ + xc0),
                             (unsigned short)(yc1 * W_ + xc1));
    }
}

// ---------------- kernel 2: gather(D) + PV(E) ----------------
__global__ __launch_bounds__(BDIM, 3) void dcn_gather(
    const float* __restrict__ xh,
    const float4* __restrict__ wtab_g,
    const ushort4* __restrict__ itab_g,
    const unsigned short* __restrict__ wB,
    float* __restrict__ out)
{
    __shared__ __align__(16) unsigned short samp_s[TP * ROWS];  // 41472 B
    __shared__ __align__(16) float4 wtab[NE];                   // 4608 B
    __shared__ ushort4        itab[NE];                         // 2304 B
    __shared__ unsigned short dsttab[NE];                       // 576 B

    const int t    = threadIdx.x;
    const int wave = t >> 6;
    const int lane = t & 63;
    const int blk  = ((blockIdx.x & 7) << 8) | (blockIdx.x >> 3);   // same swizzle
    const int wo0  = (blk & 3) * TP;
    const int ho   = (blk >> 2) & 127;
    const int b    = blk >> 9;

    const float* xb = xh + (size_t)b * HW_ * C_;

    // ---- stage tabs global -> LDS (coalesced)
    {
        const float4*  wg = wtab_g + (size_t)blk * NE;
        const ushort4* ig = itab_g + (size_t)blk * NE;
        for (int e = t; e < NE; e += BDIM) {
            wtab[e]   = wg[e];
            itab[e]   = ig[e];
            int p = e / 9, kk = e - p * 9;
            dsttab[e] = (unsigned short)(p * ROWS + kk * KKS);
        }
    }
    __syncthreads();

    // ---- D: bilinear gather, 4 ch/lane, reg-preloaded indices, depth-2 prefetch
    {
        const int c4 = (lane & 15) * 4;
        const int q  = lane >> 4;
        const float* base = xb + c4;

        ushort4 ixr[18];
        #pragma unroll
        for (int it = 0; it < 18; ++it)
            ixr[it] = itab[wave * 72 + it * 4 + q];

        #define ISSUE(itv, d00, d01, d10, d11)                       \
            { ushort4 ix_ = ixr[itv];                                \
              d00 = *(const float4*)(base + ((size_t)ix_.x << 6));   \
              d01 = *(const float4*)(base + ((size_t)ix_.y << 6));   \
              d10 = *(const float4*)(base + ((size_t)ix_.z << 6));   \
              d11 = *(const float4*)(base + ((size_t)ix_.w << 6)); }

        float4 p00, p01, p10, p11;
        ISSUE(0, p00, p01, p10, p11);
        #pragma unroll
        for (int it = 0; it < 18; ++it) {
            float4 n00, n01, n10, n11;
            if (it < 17) ISSUE(it + 1, n00, n01, n10, n11);
            const int e = wave * 72 + it * 4 + q;
            float4 wt  = wtab[e];
            int    dst = dsttab[e];
            float s0 = p00.x * wt.x;
            s0 = fmaf(p01.x, wt.y, s0); s0 = fmaf(p10.x, wt.z, s0); s0 = fmaf(p11.x, wt.w, s0);
            float s1 = p00.y * wt.x;
            s1 = fmaf(p01.y, wt.y, s1); s1 = fmaf(p10.y, wt.z, s1); s1 = fmaf(p11.y, wt.w, s1);
            float s2 = p00.z * wt.x;
            s2 = fmaf(p01.z, wt.y, s2); s2 = fmaf(p10.z, wt.z, s2); s2 = fmaf(p11.z, wt.w, s2);
            float s3 = p00.w * wt.x;
            s3 = fmaf(p01.w, wt.y, s3); s3 = fmaf(p10.w, wt.z, s3); s3 = fmaf(p11.w, wt.w, s3);
            *(uint2*)&samp_s[dst + c4] = make_uint2(pk2bf(s0, s1), pk2bf(s2, s3));
            if (it < 17) { p00 = n00; p01 = n01; p10 = n10; p11 = n11; }
        }
        #undef ISSUE
    }
    __syncthreads();

    // ---- E: out[p][o] via MFMA; 1 bp load feeds 2 pixel halves
    {
        f32x4 acc0 = {0.f, 0.f, 0.f, 0.f};
        f32x4 acc1 = {0.f, 0.f, 0.f, 0.f};
        const unsigned short* bp = wB + ((size_t)(wave * 18) * 64 + lane) * 8;
        const int arow = (lane & 15) * ROWS + (lane >> 4) * 8;
        #pragma unroll
        for (int ks = 0; ks < 18; ++ks) {
            const int ro = arow + (ks >> 1) * KKS + (ks & 1) * 32;
            short8 av0 = *(const short8*)&samp_s[ro];
            short8 av1 = *(const short8*)&samp_s[ro + 16 * ROWS];
            short8 bv  = *(const short8*)bp;  bp += 512;
            acc0 = __builtin_amdgcn_mfma_f32_16x16x32_bf16(av0, bv, acc0, 0, 0, 0);
            acc1 = __builtin_amdgcn_mfma_f32_16x16x32_bf16(av1, bv, acc1, 0, 0, 0);
        }
        int o    = wave * 16 + (lane & 15);
        int prow = (lane >> 4) * 4;
        float* ob = out + (size_t)b * O_ * HW_ + (size_t)o * HW_ + ho * W_ + wo0;
        #pragma unroll
        for (int r = 0; r < 4; ++r) {
            ob[prow + r]      = acc0[r];
            ob[16 + prow + r] = acc1[r];
        }
    }
}

// ---------------- fallback: R11 monolithic kernel (verbatim) ----------------
__global__ __launch_bounds__(BDIM, 3) void dcn_mono(
    const float* __restrict__ xh,
    const float* __restrict__ b_off,
    const float* __restrict__ b_mod,
    const unsigned short* __restrict__ wB,
    const unsigned short* __restrict__ wO,
    float* __restrict__ out)
{
    __shared__ __align__(16) unsigned short samp_s[TP * ROWS];
    __shared__ __align__(16) float4 wtab[NE];
    __shared__ ushort4        itab[NE];
    __shared__ unsigned short dsttab[NE];

    float* offs = (float*)(samp_s + 8192);
    float* msk  = offs + TP * 18;

    const int t    = threadIdx.x;
    const int wave = t >> 6;
    const int lane = t & 63;
    const int blk  = ((blockIdx.x & 7) << 8) | (blockIdx.x >> 3);
    const int wo0  = (blk & 3) * TP;
    const int ho   = (blk >> 2) & 127;
    const int b    = blk >> 9;

    const float* xb = xh + (size_t)b * HW_ * C_;

    for (int u = t; u < 102 * 16; u += BDIM) {
        int row = u >> 4;
        int c4  = (u & 15) * 4;
        int ry  = row / XCOLS;
        int col = row - ry * XCOLS;
        int gy  = ho - 1 + ry;
        int gx  = wo0 - 1 + col;
        float4 v = make_float4(0.f, 0.f, 0.f, 0.f);
        if (gy >= 0 && gy < H_ && gx >= 0 && gx < W_)
            v = *(const float4*)&xb[(size_t)(gy * W_ + gx) * C_ + c4];
        *(uint2*)&samp_s[row * XTP + c4] = make_uint2(pk2bf(v.x, v.y), pk2bf(v.z, v.w));
    }
    __syncthreads();

    if (wave < 2) {
        f32x4 acc0 = {0.f, 0.f, 0.f, 0.f};
        f32x4 acc1 = {0.f, 0.f, 0.f, 0.f};
        const unsigned short* bp = wO + ((size_t)(wave * 18) * 64 + lane) * 8;
        const unsigned short* ap = samp_s + (lane & 15) * XTP + (lane >> 4) * 8;
        #pragma unroll
        for (int ks = 0; ks < 18; ++ks) {
            const int kk = ks >> 1, ky = kk / 3, kx = kk - ky * 3;
            const int ro = (ky * XCOLS + kx) * XTP + (ks & 1) * 32;
            short8 av0 = *(const short8*)&ap[ro];
            short8 av1 = *(const short8*)&ap[ro + 16 * XTP];
            short8 bv  = *(const short8*)bp;  bp += 512;
            acc0 = __builtin_amdgcn_mfma_f32_16x16x32_bf16(av0, bv, acc0, 0, 0, 0);
            acc1 = __builtin_amdgcn_mfma_f32_16x16x32_bf16(av1, bv, acc1, 0, 0, 0);
        }
        int oc   = wave * 16 + (lane & 15);
        int prow = (lane >> 4) * 4;
        if (oc < 18) {
            float bias = b_off[oc];
            #pragma unroll
            for (int r = 0; r < 4; ++r) {
                offs[(prow + r) * 18 + oc]      = acc0[r] + bias;
                offs[(prow + 16 + r) * 18 + oc] = acc1[r] + bias;
            }
        } else if (oc < 27) {
            int mc = oc - 18;
            float bias = b_mod[mc];
            #pragma unroll
            for (int r = 0; r < 4; ++r) {
                msk[(prow + r) * KK_ + mc]      = 2.f / (1.f + expf(-(acc0[r] + bias)));
                msk[(prow + 16 + r) * KK_ + mc] = 2.f / (1.f + expf(-(acc1[r] + bias)));
            }
        }
    }
    __syncthreads();

    for (int e = t; e < NE; e += BDIM) {
        int p  = e / 9;
        int kk = e - p * 9;
        int ky = kk / 3, kx = kk - ky * 3;
        float dy = offs[p * 18 + 2 * kk];
        float dx = offs[p * 18 + 2 * kk + 1];
        float py = dy + (float)(ho - 1 + ky);
        float px = dx + (float)(wo0 + p - 1 + kx);
        float y0f = floorf(py), x0f = floorf(px);
        float wy = py - y0f,    wx = px - x0f;
        int y0 = (int)y0f, x0 = (int)x0f;
        int y1 = y0 + 1,   x1 = x0 + 1;
        float m = msk[p * KK_ + kk];
        float vy0 = (y0 >= 0 && y0 < H_) ? 1.f : 0.f;
        float vy1 = (y1 >= 0 && y1 < H_) ? 1.f : 0.f;
        float vx0 = (x0 >= 0 && x0 < W_) ? 1.f : 0.f;
        float vx1 = (x1 >= 0 && x1 < W_) ? 1.f : 0.f;
        float4 wt;
        wt.x = (1.f - wy) * (1.f - wx) * m * vy0 * vx0;
        wt.y = (1.f - wy) * wx * m * vy0 * vx1;
        wt.z = wy * (1.f - wx) * m * vy1 * vx0;
        wt.w = wy * wx * m * vy1 * vx1;
        int yc0 = min(max(y0, 0), H_ - 1), yc1 = min(max(y1, 0), H_ - 1);
        int xc0 = min(max(x0, 0), W_ - 1), xc1 = min(max(x1, 0), W_ - 1);
        wtab[e] = wt;
        itab[e] = make_ushort4((unsigned short)(yc0 * W_ + xc0),
                               (unsigned short)(yc0 * W_ + xc1),
                               (unsigned short)(yc1 * W_ + xc0),
                               (unsigned short)(yc1 * W_ + xc1));
        dsttab[e] = (unsigned short)(p * ROWS + kk * KKS);
    }
    __syncthreads();

    {
        const int c4 = (lane & 15) * 4;
        const int q  = lane >> 4;
        const float* base = xb + c4;

        ushort4 ixr[18];
        #pragma unroll
        for (int it = 0; it < 18; ++it)
            ixr[it] = itab[wave * 72 + it * 4 + q];

        #define ISSUE(itv, d00, d01, d10, d11)                       \
            { ushort4 ix_ = ixr[itv];                                \
              d00 = *(const float4*)(base + ((size_t)ix_.x << 6));   \
              d01 = *(const float4*)(base + ((size_t)ix_.y << 6));   \
              d10 = *(const float4*)(base + ((size_t)ix_.z << 6));   \
              d11 = *(const float4*)(base + ((size_t)ix_.w << 6)); }

        float4 p00, p01, p10, p11;
        ISSUE(0, p00, p01, p10, p11);
        #pragma unroll
        for (int it = 0; it < 18; ++it) {
            float4 n00, n01, n10, n11;
            if (it < 17) ISSUE(it + 1, n00, n01, n10, n11);
            const int e = wave * 72 + it * 4 + q;
            float4 wt  = wtab[e];
            int    dst = dsttab[e];
            float s0 = p00.x * wt.x;
            s0 = fmaf(p01.x, wt.y, s0); s0 = fmaf(p10.x, wt.z, s0); s0 = fmaf(p11.x, wt.w, s0);
            float s1 = p00.y * wt.x;
            s1 = fmaf(p01.y, wt.y, s1); s1 = fmaf(p10.y, wt.z, s1); s1 = fmaf(p11.y, wt.w, s1);
            float s2 = p00.z * wt.x;
            s2 = fmaf(p01.z, wt.y, s2); s2 = fmaf(p10.z, wt.z, s2); s2 = fmaf(p11.z, wt.w, s2);
            float s3 = p00.w * wt.x;
            s3 = fmaf(p01.w, wt.y, s3); s3 = fmaf(p10.w, wt.z, s3); s3 = fmaf(p11.w, wt.w, s3);
            *(uint2*)&samp_s[dst + c4] = make_uint2(pk2bf(s0, s1), pk2bf(s2, s3));
            if (it < 17) { p00 = n00; p01 = n01; p10 = n10; p11 = n11; }
        }
        #undef ISSUE
    }
    __syncthreads();

    {
        f32x4 acc0 = {0.f, 0.f, 0.f, 0.f};
        f32x4 acc1 = {0.f, 0.f, 0.f, 0.f};
        const unsigned short* bp = wB + ((size_t)(wave * 18) * 64 + lane) * 8;
        const int arow = (lane & 15) * ROWS + (lane >> 4) * 8;
        #pragma unroll
        for (int ks = 0; ks < 18; ++ks) {
            const int ro = arow + (ks >> 1) * KKS + (ks & 1) * 32;
            short8 av0 = *(const short8*)&samp_s[ro];
            short8 av1 = *(const short8*)&samp_s[ro + 16 * ROWS];
            short8 bv  = *(const short8*)bp;  bp += 512;
            acc0 = __builtin_amdgcn_mfma_f32_16x16x32_bf16(av0, bv, acc0, 0, 0, 0);
            acc1 = __builtin_amdgcn_mfma_f32_16x16x32_bf16(av1, bv, acc1, 0, 0, 0);
        }
        int o    = wave * 16 + (lane & 15);
        int prow = (lane >> 4) * 4;
        float* ob = out + (size_t)b * O_ * HW_ + (size_t)o * HW_ + ho * W_ + wo0;
        #pragma unroll
        for (int r = 0; r < 4; ++r) {
            ob[prow + r]      = acc0[r];
            ob[16 + prow + r] = acc1[r];
        }
    }
}

extern "C" void kernel_launch(void* const* d_in, const int* in_sizes, int n_in,
                              void* d_out, int out_size, void* d_ws, size_t ws_size,
                              hipStream_t stream) {
    const float* x     = (const float*)d_in[0];
    const float* w_off = (const float*)d_in[1];
    const float* b_off = (const float*)d_in[2];
    const float* w_mod = (const float*)d_in[3];
    const float* b_mod = (const float*)d_in[4];
    const float* w_reg = (const float*)d_in[5];
    float* out = (float*)d_out;

    unsigned short* wpack = (unsigned short*)d_ws;

    if (ws_size >= WS_SPLIT) {
        float4*  wtab_g = (float4*)((char*)d_ws + WTAB_OFF);
        ushort4* itab_g = (ushort4*)((char*)d_ws + ITAB_OFF);
        float*   x_hwc  = (float*)((char*)d_ws + XHWC2_OFF);
        dcn_pre<<<4096 + 216, BDIM, 0, stream>>>(x, x_hwc, w_off, w_mod, w_reg, wpack);
        dcn_tabs<<<NBLK, BDIM, 0, stream>>>(x_hwc, b_off, b_mod,
                                            wpack + 36864, wtab_g, itab_g);
        dcn_gather<<<NBLK, BDIM, 0, stream>>>(x_hwc, wtab_g, itab_g, wpack, out);
    } else {
        float* x_hwc = (float*)((char*)d_ws + XHWC_OFF);
        dcn_pre<<<4096 + 216, BDIM, 0, stream>>>(x, x_hwc, w_off, w_mod, w_reg, wpack);
        dcn_mono<<<NBLK, BDIM, 0, stream>>>(x_hwc, b_off, b_mod,
                                            wpack, wpack + 36864, out);
    }
}

// Round 13
// 46.871 us; speedup vs baseline: 1.5410x; 1.1322x over previous
//
#include <hip/hip_runtime.h>
#include <math.h>

#define BDIM 256
#define TP   32                 // output pixels per block (along W)
#define C_   64
#define O_   64
#define H_   128
#define W_   128
#define KK_  9
#define CKK  576
#define HW_  (H_ * W_)          // 16384
#define KKS  72                 // padded kk-block stride in shorts (144 B)
#define ROWS (KK_ * KKS)        // 648 shorts per pixel row (1296 B)
#define XTP  72                 // compact x-tile row pad (shorts)
#define XCOLS 34                // compact tile cols (TP + 2 halo)
#define NE   (TP * KK_)         // 288 gather entries
#define NBLK 2048

// ---- ws layout ----
#define WTAB_OFF  131072
#define ITAB_OFF  (WTAB_OFF + (size_t)NBLK * NE * 16)     //  9,568,256
#define XHWC2_OFF (ITAB_OFF + (size_t)NBLK * NE * 8)      // 14,286,848
#define XHBF_OFF  (XHWC2_OFF + (size_t)4 * HW_ * C_ * 4)  // 31,064,064
#define WS_BF16   (XHBF_OFF + (size_t)4 * HW_ * C_ * 2)   // 39,452,672
// ---- fallback monolithic path ----
#define XHWC_OFF  131072

typedef short short8 __attribute__((ext_vector_type(8)));
typedef float f32x4  __attribute__((ext_vector_type(4)));

__device__ __forceinline__ unsigned short f2bf(float f) {
    unsigned int u = __float_as_uint(f);
    u += 0x7FFFu + ((u >> 16) & 1u);          // RNE (inputs finite)
    return (unsigned short)(u >> 16);
}

// packed RNE: lo -> bits[15:0], hi -> bits[31:16]
__device__ __forceinline__ unsigned int pk2bf(float lo, float hi) {
    unsigned int r;
    asm("v_cvt_pk_bf16_f32 %0, %1, %2" : "=v"(r) : "v"(lo), "v"(hi));
    return r;
}

__device__ __forceinline__ float bf_lo(unsigned int u) { return __uint_as_float(u << 16); }
__device__ __forceinline__ float bf_hi(unsigned int u) { return __uint_as_float(u & 0xFFFF0000u); }

// ---------------- pre: fused {x NCHW->HWC fp32 transpose} + {weight pack} ----
__global__ __launch_bounds__(BDIM) void dcn_pre(
    const float* __restrict__ x, float* __restrict__ xh,
    const float* __restrict__ w_off, const float* __restrict__ w_mod,
    const float* __restrict__ w_reg, unsigned short* __restrict__ wpack)
{
    __shared__ float tile[32][33];
    if (blockIdx.x >= 4096) {
        int i = (blockIdx.x - 4096) * BDIM + threadIdx.x;
        bool isB = i < 36864;
        int r = isB ? i : i - 36864;
        int j    = r & 7;
        int lane = (r >> 3) & 63;
        int t2   = r >> 9;
        int kstep = t2 % 18;
        int tilei = t2 / 18;
        int k  = kstep * 32 + (lane >> 4) * 8 + j;
        int c  = k & 63;
        int kk = k >> 6;
        int col = tilei * 16 + (lane & 15);
        float v;
        if (isB) {
            v = w_reg[(size_t)col * CKK + c * KK_ + kk];
        } else {
            if (col < 18)      v = w_off[(size_t)col * CKK + c * KK_ + kk];
            else if (col < 27) v = w_mod[(size_t)(col - 18) * CKK + c * KK_ + kk];
            else               v = 0.f;
        }
        wpack[i] = f2bf(v);
        return;
    }
    int wq = blockIdx.x & 3;
    int cq = (blockIdx.x >> 2) & 1;
    int by = blockIdx.x >> 3;
    int b = by >> 7, y = by & 127;
    int w0 = wq * 32, c0 = cq * 32;
    int tw = threadIdx.x & 31, tc = threadIdx.x >> 5;
    const float* xp = x + (size_t)b * C_ * HW_ + (size_t)y * W_;
    #pragma unroll
    for (int k = 0; k < 4; ++k)
        tile[tc + k * 8][tw] = xp[(size_t)(c0 + tc + k * 8) * HW_ + w0 + tw];
    __syncthreads();
    float* op = xh + ((size_t)b * HW_ + (size_t)y * W_) * C_;
    #pragma unroll
    for (int k = 0; k < 4; ++k)
        op[(size_t)(w0 + tc + k * 8) * C_ + c0 + tw] = tile[tw][tc + k * 8];
}

// ------- kernel 1: tabs = A + B + C (blocks < NBLK) ; x_hwc->x_hbf halver (rest) -------
__global__ __launch_bounds__(BDIM, 4) void dcn_tabs(
    const float* __restrict__ xh,
    unsigned short* __restrict__ xhbf,
    const float* __restrict__ b_off,
    const float* __restrict__ b_mod,
    const unsigned short* __restrict__ wO,
    float4* __restrict__ wtab_g,
    ushort4* __restrict__ itab_g)
{
    __shared__ __align__(16) unsigned short xtile[102 * XTP];   // 14688 B
    __shared__ float offs[TP * 18];                             // 2304 B
    __shared__ float msk [TP * KK_];                            // 1152 B

    if (blockIdx.x >= NBLK) {
        // ---- halver: linear fp32 -> bf16 (4*HW*C = 4,194,304 floats; 8/thread)
        int i = (blockIdx.x - NBLK) * BDIM + threadIdx.x;       // 0..524287
        const float4* src = (const float4*)xh;
        float4 a = src[(size_t)i * 2];
        float4 c = src[(size_t)i * 2 + 1];
        ((uint4*)xhbf)[i] = make_uint4(pk2bf(a.x, a.y), pk2bf(a.z, a.w),
                                       pk2bf(c.x, c.y), pk2bf(c.z, c.w));
        return;
    }

    const int t    = threadIdx.x;
    const int wave = t >> 6;
    const int lane = t & 63;
    const int blk  = ((blockIdx.x & 7) << 8) | (blockIdx.x >> 3);   // XCD swizzle
    const int wo0  = (blk & 3) * TP;
    const int ho   = (blk >> 2) & 127;
    const int b    = blk >> 9;

    const float* xb = xh + (size_t)b * HW_ * C_;

    // ---- A
    for (int u = t; u < 102 * 16; u += BDIM) {
        int row = u >> 4;
        int c4  = (u & 15) * 4;
        int ry  = row / XCOLS;
        int col = row - ry * XCOLS;
        int gy  = ho - 1 + ry;
        int gx  = wo0 - 1 + col;
        float4 v = make_float4(0.f, 0.f, 0.f, 0.f);
        if (gy >= 0 && gy < H_ && gx >= 0 && gx < W_)
            v = *(const float4*)&xb[(size_t)(gy * W_ + gx) * C_ + c4];
        *(uint2*)&xtile[row * XTP + c4] = make_uint2(pk2bf(v.x, v.y), pk2bf(v.z, v.w));
    }
    __syncthreads();

    // ---- B
    if (wave < 2) {
        f32x4 acc0 = {0.f, 0.f, 0.f, 0.f};
        f32x4 acc1 = {0.f, 0.f, 0.f, 0.f};
        const unsigned short* bp = wO + ((size_t)(wave * 18) * 64 + lane) * 8;
        const unsigned short* ap = xtile + (lane & 15) * XTP + (lane >> 4) * 8;
        #pragma unroll
        for (int ks = 0; ks < 18; ++ks) {
            const int kk = ks >> 1, ky = kk / 3, kx = kk - ky * 3;
            const int ro = (ky * XCOLS + kx) * XTP + (ks & 1) * 32;
            short8 av0 = *(const short8*)&ap[ro];
            short8 av1 = *(const short8*)&ap[ro + 16 * XTP];
            short8 bv  = *(const short8*)bp;  bp += 512;
            acc0 = __builtin_amdgcn_mfma_f32_16x16x32_bf16(av0, bv, acc0, 0, 0, 0);
            acc1 = __builtin_amdgcn_mfma_f32_16x16x32_bf16(av1, bv, acc1, 0, 0, 0);
        }
        int oc   = wave * 16 + (lane & 15);
        int prow = (lane >> 4) * 4;
        if (oc < 18) {
            float bias = b_off[oc];
            #pragma unroll
            for (int r = 0; r < 4; ++r) {
                offs[(prow + r) * 18 + oc]      = acc0[r] + bias;
                offs[(prow + 16 + r) * 18 + oc] = acc1[r] + bias;
            }
        } else if (oc < 27) {
            int mc = oc - 18;
            float bias = b_mod[mc];
            #pragma unroll
            for (int r = 0; r < 4; ++r) {
                msk[(prow + r) * KK_ + mc]      = 2.f / (1.f + expf(-(acc0[r] + bias)));
                msk[(prow + 16 + r) * KK_ + mc] = 2.f / (1.f + expf(-(acc1[r] + bias)));
            }
        }
    }
    __syncthreads();

    // ---- C -> global tabs
    float4*  wg = wtab_g + (size_t)blk * NE;
    ushort4* ig = itab_g + (size_t)blk * NE;
    for (int e = t; e < NE; e += BDIM) {
        int p  = e / 9;
        int kk = e - p * 9;
        int ky = kk / 3, kx = kk - ky * 3;
        float dy = offs[p * 18 + 2 * kk];
        float dx = offs[p * 18 + 2 * kk + 1];
        float py = dy + (float)(ho - 1 + ky);
        float px = dx + (float)(wo0 + p - 1 + kx);
        float y0f = floorf(py), x0f = floorf(px);
        float wy = py - y0f,    wx = px - x0f;
        int y0 = (int)y0f, x0 = (int)x0f;
        int y1 = y0 + 1,   x1 = x0 + 1;
        float m = msk[p * KK_ + kk];
        float vy0 = (y0 >= 0 && y0 < H_) ? 1.f : 0.f;
        float vy1 = (y1 >= 0 && y1 < H_) ? 1.f : 0.f;
        float vx0 = (x0 >= 0 && x0 < W_) ? 1.f : 0.f;
        float vx1 = (x1 >= 0 && x1 < W_) ? 1.f : 0.f;
        float4 wt;
        wt.x = (1.f - wy) * (1.f - wx) * m * vy0 * vx0;
        wt.y = (1.f - wy) * wx * m * vy0 * vx1;
        wt.z = wy * (1.f - wx) * m * vy1 * vx0;
        wt.w = wy * wx * m * vy1 * vx1;
        int yc0 = min(max(y0, 0), H_ - 1), yc1 = min(max(y1, 0), H_ - 1);
        int xc0 = min(max(x0, 0), W_ - 1), xc1 = min(max(x1, 0), W_ - 1);
        wg[e] = wt;
        ig[e] = make_ushort4((unsigned short)(yc0 * W_ + xc0),
                             (unsigned short)(yc0 * W_ + xc1),
                             (unsigned short)(yc1 * W_ + xc0),
                             (unsigned short)(yc1 * W_ + xc1));
    }
}

// ---------------- kernel 2: gather(D, bf16 corners 8ch/lane) + PV(E) ----------------
__global__ __launch_bounds__(BDIM, 3) void dcn_gather(
    const unsigned short* __restrict__ xhbf,
    const float4* __restrict__ wtab_g,
    const ushort4* __restrict__ itab_g,
    const unsigned short* __restrict__ wB,
    float* __restrict__ out)
{
    __shared__ __align__(16) unsigned short samp_s[TP * ROWS];  // 41472 B
    __shared__ __align__(16) float4 wtab[NE];                   // 4608 B
    __shared__ ushort4        itab[NE];                         // 2304 B
    __shared__ unsigned short dsttab[NE];                       // 576 B

    const int t    = threadIdx.x;
    const int wave = t >> 6;
    const int lane = t & 63;
    const int blk  = ((blockIdx.x & 7) << 8) | (blockIdx.x >> 3);   // same swizzle
    const int wo0  = (blk & 3) * TP;
    const int ho   = (blk >> 2) & 127;
    const int b    = blk >> 9;

    const unsigned short* xbh = xhbf + (size_t)b * HW_ * C_;

    // ---- stage tabs global -> LDS (coalesced)
    {
        const float4*  wg = wtab_g + (size_t)blk * NE;
        const ushort4* ig = itab_g + (size_t)blk * NE;
        for (int e = t; e < NE; e += BDIM) {
            wtab[e]   = wg[e];
            itab[e]   = ig[e];
            int p = e / 9, kk = e - p * 9;
            dsttab[e] = (unsigned short)(p * ROWS + kk * KKS);
        }
    }
    __syncthreads();

    // ---- D: bilinear gather from bf16 HWC, 8 ch/lane (8 lanes per entry)
    {
        const int c8 = (lane & 7) * 8;
        const int q  = lane >> 3;                 // 0..7
        const unsigned short* base = xbh + c8;

        ushort4 ixr[9];
        #pragma unroll
        for (int it = 0; it < 9; ++it)
            ixr[it] = itab[wave * 72 + it * 8 + q];

        #pragma unroll
        for (int it = 0; it < 9; ++it) {
            const int e = wave * 72 + it * 8 + q;
            float4  wt  = wtab[e];
            int     dst = dsttab[e];
            ushort4 ix  = ixr[it];
            uint4 u00 = *(const uint4*)(base + ((size_t)ix.x << 6));
            uint4 u01 = *(const uint4*)(base + ((size_t)ix.y << 6));
            uint4 u10 = *(const uint4*)(base + ((size_t)ix.z << 6));
            uint4 u11 = *(const uint4*)(base + ((size_t)ix.w << 6));
            const unsigned int a00[4] = {u00.x, u00.y, u00.z, u00.w};
            const unsigned int a01[4] = {u01.x, u01.y, u01.z, u01.w};
            const unsigned int a10[4] = {u10.x, u10.y, u10.z, u10.w};
            const unsigned int a11[4] = {u11.x, u11.y, u11.z, u11.w};
            unsigned int pk[4];
            #pragma unroll
            for (int wd = 0; wd < 4; ++wd) {
                float slo = bf_lo(a00[wd]) * wt.x;
                slo = fmaf(bf_lo(a01[wd]), wt.y, slo);
                slo = fmaf(bf_lo(a10[wd]), wt.z, slo);
                slo = fmaf(bf_lo(a11[wd]), wt.w, slo);
                float shi = bf_hi(a00[wd]) * wt.x;
                shi = fmaf(bf_hi(a01[wd]), wt.y, shi);
                shi = fmaf(bf_hi(a10[wd]), wt.z, shi);
                shi = fmaf(bf_hi(a11[wd]), wt.w, shi);
                pk[wd] = pk2bf(slo, shi);
            }
            *(uint4*)&samp_s[dst + c8] = make_uint4(pk[0], pk[1], pk[2], pk[3]);
        }
    }
    __syncthreads();

    // ---- E: out[p][o] via MFMA; 1 bp load feeds 2 pixel halves
    {
        f32x4 acc0 = {0.f, 0.f, 0.f, 0.f};
        f32x4 acc1 = {0.f, 0.f, 0.f, 0.f};
        const unsigned short* bp = wB + ((size_t)(wave * 18) * 64 + lane) * 8;
        const int arow = (lane & 15) * ROWS + (lane >> 4) * 8;
        #pragma unroll
        for (int ks = 0; ks < 18; ++ks) {
            const int ro = arow + (ks >> 1) * KKS + (ks & 1) * 32;
            short8 av0 = *(const short8*)&samp_s[ro];
            short8 av1 = *(const short8*)&samp_s[ro + 16 * ROWS];
            short8 bv  = *(const short8*)bp;  bp += 512;
            acc0 = __builtin_amdgcn_mfma_f32_16x16x32_bf16(av0, bv, acc0, 0, 0, 0);
            acc1 = __builtin_amdgcn_mfma_f32_16x16x32_bf16(av1, bv, acc1, 0, 0, 0);
        }
        int o    = wave * 16 + (lane & 15);
        int prow = (lane >> 4) * 4;
        float* ob = out + (size_t)b * O_ * HW_ + (size_t)o * HW_ + ho * W_ + wo0;
        #pragma unroll
        for (int r = 0; r < 4; ++r) {
            ob[prow + r]      = acc0[r];
            ob[16 + prow + r] = acc1[r];
        }
    }
}

// ---------------- fallback: monolithic kernel (R11, verbatim) ----------------
__global__ __launch_bounds__(BDIM, 3) void dcn_mono(
    const float* __restrict__ xh,
    const float* __restrict__ b_off,
    const float* __restrict__ b_mod,
    const unsigned short* __restrict__ wB,
    const unsigned short* __restrict__ wO,
    float* __restrict__ out)
{
    __shared__ __align__(16) unsigned short samp_s[TP * ROWS];
    __shared__ __align__(16) float4 wtab[NE];
    __shared__ ushort4        itab[NE];
    __shared__ unsigned short dsttab[NE];

    float* offs = (float*)(samp_s + 8192);
    float* msk  = offs + TP * 18;

    const int t    = threadIdx.x;
    const int wave = t >> 6;
    const int lane = t & 63;
    const int blk  = ((blockIdx.x & 7) << 8) | (blockIdx.x >> 3);
    const int wo0  = (blk & 3) * TP;
    const int ho   = (blk >> 2) & 127;
    const int b    = blk >> 9;

    const float* xb = xh + (size_t)b * HW_ * C_;

    for (int u = t; u < 102 * 16; u += BDIM) {
        int row = u >> 4;
        int c4  = (u & 15) * 4;
        int ry  = row / XCOLS;
        int col = row - ry * XCOLS;
        int gy  = ho - 1 + ry;
        int gx  = wo0 - 1 + col;
        float4 v = make_float4(0.f, 0.f, 0.f, 0.f);
        if (gy >= 0 && gy < H_ && gx >= 0 && gx < W_)
            v = *(const float4*)&xb[(size_t)(gy * W_ + gx) * C_ + c4];
        *(uint2*)&samp_s[row * XTP + c4] = make_uint2(pk2bf(v.x, v.y), pk2bf(v.z, v.w));
    }
    __syncthreads();

    if (wave < 2) {
        f32x4 acc0 = {0.f, 0.f, 0.f, 0.f};
        f32x4 acc1 = {0.f, 0.f, 0.f, 0.f};
        const unsigned short* bp = wO + ((size_t)(wave * 18) * 64 + lane) * 8;
        const unsigned short* ap = samp_s + (lane & 15) * XTP + (lane >> 4) * 8;
        #pragma unroll
        for (int ks = 0; ks < 18; ++ks) {
            const int kk = ks >> 1, ky = kk / 3, kx = kk - ky * 3;
            const int ro = (ky * XCOLS + kx) * XTP + (ks & 1) * 32;
            short8 av0 = *(const short8*)&ap[ro];
            short8 av1 = *(const short8*)&ap[ro + 16 * XTP];
            short8 bv  = *(const short8*)bp;  bp += 512;
            acc0 = __builtin_amdgcn_mfma_f32_16x16x32_bf16(av0, bv, acc0, 0, 0, 0);
            acc1 = __builtin_amdgcn_mfma_f32_16x16x32_bf16(av1, bv, acc1, 0, 0, 0);
        }
        int oc   = wave * 16 + (lane & 15);
        int prow = (lane >> 4) * 4;
        if (oc < 18) {
            float bias = b_off[oc];
            #pragma unroll
            for (int r = 0; r < 4; ++r) {
                offs[(prow + r) * 18 + oc]      = acc0[r] + bias;
                offs[(prow + 16 + r) * 18 + oc] = acc1[r] + bias;
            }
        } else if (oc < 27) {
            int mc = oc - 18;
            float bias = b_mod[mc];
            #pragma unroll
            for (int r = 0; r < 4; ++r) {
                msk[(prow + r) * KK_ + mc]      = 2.f / (1.f + expf(-(acc0[r] + bias)));
                msk[(prow + 16 + r) * KK_ + mc] = 2.f / (1.f + expf(-(acc1[r] + bias)));
            }
        }
    }
    __syncthreads();

    for (int e = t; e < NE; e += BDIM) {
        int p  = e / 9;
        int kk = e - p * 9;
        int ky = kk / 3, kx = kk - ky * 3;
        float dy = offs[p * 18 + 2 * kk];
        float dx = offs[p * 18 + 2 * kk + 1];
        float py = dy + (float)(ho - 1 + ky);
        float px = dx + (float)(wo0 + p - 1 + kx);
        float y0f = floorf(py), x0f = floorf(px);
        float wy = py - y0f,    wx = px - x0f;
        int y0 = (int)y0f, x0 = (int)x0f;
        int y1 = y0 + 1,   x1 = x0 + 1;
        float m = msk[p * KK_ + kk];
        float vy0 = (y0 >= 0 && y0 < H_) ? 1.f : 0.f;
        float vy1 = (y1 >= 0 && y1 < H_) ? 1.f : 0.f;
        float vx0 = (x0 >= 0 && x0 < W_) ? 1.f : 0.f;
        float vx1 = (x1 >= 0 && x1 < W_) ? 1.f : 0.f;
        float4 wt;
        wt.x = (1.f - wy) * (1.f - wx) * m * vy0 * vx0;
        wt.y = (1.f - wy) * wx * m * vy0 * vx1;
        wt.z = wy * (1.f - wx) * m * vy1 * vx0;
        wt.w = wy * wx * m * vy1 * vx1;
        int yc0 = min(max(y0, 0), H_ - 1), yc1 = min(max(y1, 0), H_ - 1);
        int xc0 = min(max(x0, 0), W_ - 1), xc1 = min(max(x1, 0), W_ - 1);
        wtab[e] = wt;
        itab[e] = make_ushort4((unsigned short)(yc0 * W_ + xc0),
                               (unsigned short)(yc0 * W_ + xc1),
                               (unsigned short)(yc1 * W_ + xc0),
                               (unsigned short)(yc1 * W_ + xc1));
        dsttab[e] = (unsigned short)(p * ROWS + kk * KKS);
    }
    __syncthreads();

    {
        const int c4 = (lane & 15) * 4;
        const int q  = lane >> 4;
        const float* base = xb + c4;

        ushort4 ixr[18];
        #pragma unroll
        for (int it = 0; it < 18; ++it)
            ixr[it] = itab[wave * 72 + it * 4 + q];

        #define ISSUE(itv, d00, d01, d10, d11)                       \
            { ushort4 ix_ = ixr[itv];                                \
              d00 = *(const float4*)(base + ((size_t)ix_.x << 6));   \
              d01 = *(const float4*)(base + ((size_t)ix_.y << 6));   \
              d10 = *(const float4*)(base + ((size_t)ix_.z << 6));   \
              d11 = *(const float4*)(base + ((size_t)ix_.w << 6)); }

        float4 p00, p01, p10, p11;
        ISSUE(0, p00, p01, p10, p11);
        #pragma unroll
        for (int it = 0; it < 18; ++it) {
            float4 n00, n01, n10, n11;
            if (it < 17) ISSUE(it + 1, n00, n01, n10, n11);
            const int e = wave * 72 + it * 4 + q;
            float4 wt  = wtab[e];
            int    dst = dsttab[e];
            float s0 = p00.x * wt.x;
            s0 = fmaf(p01.x, wt.y, s0); s0 = fmaf(p10.x, wt.z, s0); s0 = fmaf(p11.x, wt.w, s0);
            float s1 = p00.y * wt.x;
            s1 = fmaf(p01.y, wt.y, s1); s1 = fmaf(p10.y, wt.z, s1); s1 = fmaf(p11.y, wt.w, s1);
            float s2 = p00.z * wt.x;
            s2 = fmaf(p01.z, wt.y, s2); s2 = fmaf(p10.z, wt.z, s2); s2 = fmaf(p11.z, wt.w, s2);
            float s3 = p00.w * wt.x;
            s3 = fmaf(p01.w, wt.y, s3); s3 = fmaf(p10.w, wt.z, s3); s3 = fmaf(p11.w, wt.w, s3);
            *(uint2*)&samp_s[dst + c4] = make_uint2(pk2bf(s0, s1), pk2bf(s2, s3));
            if (it < 17) { p00 = n00; p01 = n01; p10 = n10; p11 = n11; }
        }
        #undef ISSUE
    }
    __syncthreads();

    {
        f32x4 acc0 = {0.f, 0.f, 0.f, 0.f};
        f32x4 acc1 = {0.f, 0.f, 0.f, 0.f};
        const unsigned short* bp = wB + ((size_t)(wave * 18) * 64 + lane) * 8;
        const int arow = (lane & 15) * ROWS + (lane >> 4) * 8;
        #pragma unroll
        for (int ks = 0; ks < 18; ++ks) {
            const int ro = arow + (ks >> 1) * KKS + (ks & 1) * 32;
            short8 av0 = *(const short8*)&samp_s[ro];
            short8 av1 = *(const short8*)&samp_s[ro + 16 * ROWS];
            short8 bv  = *(const short8*)bp;  bp += 512;
            acc0 = __builtin_amdgcn_mfma_f32_16x16x32_bf16(av0, bv, acc0, 0, 0, 0);
            acc1 = __builtin_amdgcn_mfma_f32_16x16x32_bf16(av1, bv, acc1, 0, 0, 0);
        }
        int o    = wave * 16 + (lane & 15);
        int prow = (lane >> 4) * 4;
        float* ob = out + (size_t)b * O_ * HW_ + (size_t)o * HW_ + ho * W_ + wo0;
        #pragma unroll
        for (int r = 0; r < 4; ++r) {
            ob[prow + r]      = acc0[r];
            ob[16 + prow + r] = acc1[r];
        }
    }
}

extern "C" void kernel_launch(void* const* d_in, const int* in_sizes, int n_in,
                              void* d_out, int out_size, void* d_ws, size_t ws_size,
                              hipStream_t stream) {
    const float* x     = (const float*)d_in[0];
    const float* w_off = (const float*)d_in[1];
    const float* b_off = (const float*)d_in[2];
    const float* w_mod = (const float*)d_in[3];
    const float* b_mod = (const float*)d_in[4];
    const float* w_reg = (const float*)d_in[5];
    float* out = (float*)d_out;

    unsigned short* wpack = (unsigned short*)d_ws;

    if (ws_size >= WS_BF16) {
        float4*  wtab_g = (float4*)((char*)d_ws + WTAB_OFF);
        ushort4* itab_g = (ushort4*)((char*)d_ws + ITAB_OFF);
        float*   x_hwc  = (float*)((char*)d_ws + XHWC2_OFF);
        unsigned short* x_hbf = (unsigned short*)((char*)d_ws + XHBF_OFF);
        dcn_pre<<<4096 + 216, BDIM, 0, stream>>>(x, x_hwc, w_off, w_mod, w_reg, wpack);
        dcn_tabs<<<NBLK + 2048, BDIM, 0, stream>>>(x_hwc, x_hbf, b_off, b_mod,
                                                   wpack + 36864, wtab_g, itab_g);
        dcn_gather<<<NBLK, BDIM, 0, stream>>>(x_hbf, wtab_g, itab_g, wpack, out);
    } else {
        float* x_hwc = (float*)((char*)d_ws + XHWC_OFF);
        dcn_pre<<<4096 + 216, BDIM, 0, stream>>>(x, x_hwc, w_off, w_mod, w_reg, wpack);
        dcn_mono<<<NBLK, BDIM, 0, stream>>>(x_hwc, b_off, b_mod,
                                            wpack, wpack + 36864, out);
    }
}

// Round 14
// 42.719 us; speedup vs baseline: 1.6908x; 1.0972x over previous
//
#include <hip/hip_runtime.h>
#include <math.h>

#define BDIM 256
#define TP   32                 // output pixels per block (along W)
#define C_   64
#define O_   64
#define H_   128
#define W_   128
#define KK_  9
#define CKK  576
#define HW_  (H_ * W_)          // 16384
#define KKS  72                 // padded kk-block stride in shorts (144 B)
#define ROWS (KK_ * KKS)        // 648 shorts per pixel row (1296 B)
#define XTP  72                 // compact x-tile row pad (shorts)
#define XCOLS 34                // compact tile cols (TP + 2 halo)
#define NE   (TP * KK_)         // 288 gather entries
#define NBLK 2048

// ---- ws layout (split bf16 path) ----
#define WTAB_OFF  131072
#define ITAB_OFF  (WTAB_OFF + (size_t)NBLK * NE * 16)     //  9,568,256
#define XHBF_OFF  (ITAB_OFF + (size_t)NBLK * NE * 8)      // 14,286,848
#define WS_NEED   (XHBF_OFF + (size_t)4 * HW_ * C_ * 2)   // 22,675,456
// ---- fallback monolithic path ----
#define XHWC_OFF  131072

typedef short short8 __attribute__((ext_vector_type(8)));
typedef float f32x4  __attribute__((ext_vector_type(4)));

__device__ __forceinline__ unsigned short f2bf(float f) {
    unsigned int u = __float_as_uint(f);
    u += 0x7FFFu + ((u >> 16) & 1u);          // RNE (inputs finite)
    return (unsigned short)(u >> 16);
}

// packed RNE: lo -> bits[15:0], hi -> bits[31:16]
__device__ __forceinline__ unsigned int pk2bf(float lo, float hi) {
    unsigned int r;
    asm("v_cvt_pk_bf16_f32 %0, %1, %2" : "=v"(r) : "v"(lo), "v"(hi));
    return r;
}

__device__ __forceinline__ float bf_lo(unsigned int u) { return __uint_as_float(u << 16); }
__device__ __forceinline__ float bf_hi(unsigned int u) { return __uint_as_float(u & 0xFFFF0000u); }

// ---------------- pre: {x NCHW -> HWC transpose (bf16 or fp32)} + {weight pack} ----
// mode 0: write bf16 x_hbf only (split path). mode 1: write fp32 x_hwc only (fallback).
__global__ __launch_bounds__(BDIM) void dcn_pre(
    const float* __restrict__ x, float* __restrict__ xh,
    unsigned short* __restrict__ xhbf, int mode,
    const float* __restrict__ w_off, const float* __restrict__ w_mod,
    const float* __restrict__ w_reg, unsigned short* __restrict__ wpack)
{
    __shared__ float tile[32][33];
    if (blockIdx.x >= 4096) {
        // ---- weight pack (216 blocks * 256 = 55296 threads)
        int i = (blockIdx.x - 4096) * BDIM + threadIdx.x;
        bool isB = i < 36864;
        int r = isB ? i : i - 36864;
        int j    = r & 7;
        int lane = (r >> 3) & 63;
        int t2   = r >> 9;
        int kstep = t2 % 18;
        int tilei = t2 / 18;
        int k  = kstep * 32 + (lane >> 4) * 8 + j;
        int c  = k & 63;
        int kk = k >> 6;
        int col = tilei * 16 + (lane & 15);
        float v;
        if (isB) {
            v = w_reg[(size_t)col * CKK + c * KK_ + kk];
        } else {
            if (col < 18)      v = w_off[(size_t)col * CKK + c * KK_ + kk];
            else if (col < 27) v = w_mod[(size_t)(col - 18) * CKK + c * KK_ + kk];
            else               v = 0.f;
        }
        wpack[i] = f2bf(v);
        return;
    }
    // ---- transpose one (b, y, 32w, 32c) tile
    int wq = blockIdx.x & 3;           // W/32
    int cq = (blockIdx.x >> 2) & 1;    // C/32
    int by = blockIdx.x >> 3;          // b*H + y
    int b = by >> 7, y = by & 127;
    int w0 = wq * 32, c0 = cq * 32;
    int tw = threadIdx.x & 31, tc = threadIdx.x >> 5;
    const float* xp = x + (size_t)b * C_ * HW_ + (size_t)y * W_;
    #pragma unroll
    for (int k = 0; k < 4; ++k)
        tile[tc + k * 8][tw] = xp[(size_t)(c0 + tc + k * 8) * HW_ + w0 + tw];
    __syncthreads();
    if (mode == 0) {
        // bf16 store: u in [0,512) covers ALL (wp 0..31) x (cp 0..15) -> full 32w x 32c
        unsigned int* opb = (unsigned int*)xhbf + ((size_t)b * HW_ + (size_t)y * W_) * 32;
        for (int u = threadIdx.x; u < 512; u += BDIM) {
            int wp = u >> 4;          // 0..31
            int cp = u & 15;          // 0..15 (channel pair within 32-ch slab)
            opb[(size_t)(w0 + wp) * 32 + (c0 >> 1) + cp] =
                pk2bf(tile[2 * cp][wp], tile[2 * cp + 1][wp]);
        }
    } else {
        float* op = xh + ((size_t)b * HW_ + (size_t)y * W_) * C_;
        #pragma unroll
        for (int k = 0; k < 4; ++k)
            op[(size_t)(w0 + tc + k * 8) * C_ + c0 + tw] = tile[tw][tc + k * 8];
    }
}

// ------- kernel 1: tabs = A + B + C (reads bf16 x_hbf; A is a pure copy) -------
__global__ __launch_bounds__(BDIM, 4) void dcn_tabs(
    const unsigned short* __restrict__ xhbf,
    const float* __restrict__ b_off,
    const float* __restrict__ b_mod,
    const unsigned short* __restrict__ wO,
    float4* __restrict__ wtab_g,
    ushort4* __restrict__ itab_g)
{
    __shared__ __align__(16) unsigned short xtile[102 * XTP];   // 14688 B
    __shared__ float offs[TP * 18];                             // 2304 B
    __shared__ float msk [TP * KK_];                            // 1152 B

    const int t    = threadIdx.x;
    const int wave = t >> 6;
    const int lane = t & 63;
    const int blk  = ((blockIdx.x & 7) << 8) | (blockIdx.x >> 3);   // XCD swizzle
    const int wo0  = (blk & 3) * TP;
    const int ho   = (blk >> 2) & 127;
    const int b    = blk >> 9;

    const unsigned short* xbh = xhbf + (size_t)b * HW_ * C_;

    // ---- A: copy bf16 tile (8 ch per uint4 item)
    for (int u = t; u < 102 * 8; u += BDIM) {
        int row = u >> 3;
        int c8  = (u & 7) * 8;
        int ry  = row / XCOLS;
        int col = row - ry * XCOLS;
        int gy  = ho - 1 + ry;
        int gx  = wo0 - 1 + col;
        uint4 v = make_uint4(0u, 0u, 0u, 0u);
        if (gy >= 0 && gy < H_ && gx >= 0 && gx < W_)
            v = *(const uint4*)&xbh[((size_t)(gy * W_ + gx) << 6) + c8];
        *(uint4*)&xtile[row * XTP + c8] = v;
    }
    __syncthreads();

    // ---- B: offset(18)+mask(9) conv via MFMA; 1 bp load feeds 2 pixel halves
    if (wave < 2) {
        f32x4 acc0 = {0.f, 0.f, 0.f, 0.f};
        f32x4 acc1 = {0.f, 0.f, 0.f, 0.f};
        const unsigned short* bp = wO + ((size_t)(wave * 18) * 64 + lane) * 8;
        const unsigned short* ap = xtile + (lane & 15) * XTP + (lane >> 4) * 8;
        #pragma unroll
        for (int ks = 0; ks < 18; ++ks) {
            const int kk = ks >> 1, ky = kk / 3, kx = kk - ky * 3;
            const int ro = (ky * XCOLS + kx) * XTP + (ks & 1) * 32;
            short8 av0 = *(const short8*)&ap[ro];
            short8 av1 = *(const short8*)&ap[ro + 16 * XTP];
            short8 bv  = *(const short8*)bp;  bp += 512;
            acc0 = __builtin_amdgcn_mfma_f32_16x16x32_bf16(av0, bv, acc0, 0, 0, 0);
            acc1 = __builtin_amdgcn_mfma_f32_16x16x32_bf16(av1, bv, acc1, 0, 0, 0);
        }
        int oc   = wave * 16 + (lane & 15);
        int prow = (lane >> 4) * 4;
        if (oc < 18) {
            float bias = b_off[oc];
            #pragma unroll
            for (int r = 0; r < 4; ++r) {
                offs[(prow + r) * 18 + oc]      = acc0[r] + bias;
                offs[(prow + 16 + r) * 18 + oc] = acc1[r] + bias;
            }
        } else if (oc < 27) {
            int mc = oc - 18;
            float bias = b_mod[mc];
            #pragma unroll
            for (int r = 0; r < 4; ++r) {
                msk[(prow + r) * KK_ + mc]      = 2.f / (1.f + expf(-(acc0[r] + bias)));
                msk[(prow + 16 + r) * KK_ + mc] = 2.f / (1.f + expf(-(acc1[r] + bias)));
            }
        }
    }
    __syncthreads();

    // ---- C -> global tabs
    float4*  wg = wtab_g + (size_t)blk * NE;
    ushort4* ig = itab_g + (size_t)blk * NE;
    for (int e = t; e < NE; e += BDIM) {
        int p  = e / 9;
        int kk = e - p * 9;
        int ky = kk / 3, kx = kk - ky * 3;
        float dy = offs[p * 18 + 2 * kk];
        float dx = offs[p * 18 + 2 * kk + 1];
        float py = dy + (float)(ho - 1 + ky);
        float px = dx + (float)(wo0 + p - 1 + kx);
        float y0f = floorf(py), x0f = floorf(px);
        float wy = py - y0f,    wx = px - x0f;
        int y0 = (int)y0f, x0 = (int)x0f;
        int y1 = y0 + 1,   x1 = x0 + 1;
        float m = msk[p * KK_ + kk];
        float vy0 = (y0 >= 0 && y0 < H_) ? 1.f : 0.f;
        float vy1 = (y1 >= 0 && y1 < H_) ? 1.f : 0.f;
        float vx0 = (x0 >= 0 && x0 < W_) ? 1.f : 0.f;
        float vx1 = (x1 >= 0 && x1 < W_) ? 1.f : 0.f;
        float4 wt;
        wt.x = (1.f - wy) * (1.f - wx) * m * vy0 * vx0;
        wt.y = (1.f - wy) * wx * m * vy0 * vx1;
        wt.z = wy * (1.f - wx) * m * vy1 * vx0;
        wt.w = wy * wx * m * vy1 * vx1;
        int yc0 = min(max(y0, 0), H_ - 1), yc1 = min(max(y1, 0), H_ - 1);
        int xc0 = min(max(x0, 0), W_ - 1), xc1 = min(max(x1, 0), W_ - 1);
        wg[e] = wt;
        ig[e] = make_ushort4((unsigned short)(yc0 * W_ + xc0),
                             (unsigned short)(yc0 * W_ + xc1),
                             (unsigned short)(yc1 * W_ + xc0),
                             (unsigned short)(yc1 * W_ + xc1));
    }
}

// ---------------- kernel 2: gather(D, bf16 corners 8ch/lane) + PV(E) — R13 verbatim ----
__global__ __launch_bounds__(BDIM, 3) void dcn_gather(
    const unsigned short* __restrict__ xhbf,
    const float4* __restrict__ wtab_g,
    const ushort4* __restrict__ itab_g,
    const unsigned short* __restrict__ wB,
    float* __restrict__ out)
{
    __shared__ __align__(16) unsigned short samp_s[TP * ROWS];  // 41472 B
    __shared__ __align__(16) float4 wtab[NE];                   // 4608 B
    __shared__ ushort4        itab[NE];                         // 2304 B
    __shared__ unsigned short dsttab[NE];                       // 576 B

    const int t    = threadIdx.x;
    const int wave = t >> 6;
    const int lane = t & 63;
    const int blk  = ((blockIdx.x & 7) << 8) | (blockIdx.x >> 3);   // same swizzle
    const int wo0  = (blk & 3) * TP;
    const int ho   = (blk >> 2) & 127;
    const int b    = blk >> 9;

    const unsigned short* xbh = xhbf + (size_t)b * HW_ * C_;

    // ---- stage tabs global -> LDS (coalesced)
    {
        const float4*  wg = wtab_g + (size_t)blk * NE;
        const ushort4* ig = itab_g + (size_t)blk * NE;
        for (int e = t; e < NE; e += BDIM) {
            wtab[e]   = wg[e];
            itab[e]   = ig[e];
            int p = e / 9, kk = e - p * 9;
            dsttab[e] = (unsigned short)(p * ROWS + kk * KKS);
        }
    }
    __syncthreads();

    // ---- D: bilinear gather from bf16 HWC, 8 ch/lane (8 lanes per entry)
    {
        const int c8 = (lane & 7) * 8;
        const int q  = lane >> 3;                 // 0..7
        const unsigned short* base = xbh + c8;

        ushort4 ixr[9];
        #pragma unroll
        for (int it = 0; it < 9; ++it)
            ixr[it] = itab[wave * 72 + it * 8 + q];

        #pragma unroll
        for (int it = 0; it < 9; ++it) {
            const int e = wave * 72 + it * 8 + q;
            float4  wt  = wtab[e];
            int     dst = dsttab[e];
            ushort4 ix  = ixr[it];
            uint4 u00 = *(const uint4*)(base + ((size_t)ix.x << 6));
            uint4 u01 = *(const uint4*)(base + ((size_t)ix.y << 6));
            uint4 u10 = *(const uint4*)(base + ((size_t)ix.z << 6));
            uint4 u11 = *(const uint4*)(base + ((size_t)ix.w << 6));
            const unsigned int a00[4] = {u00.x, u00.y, u00.z, u00.w};
            const unsigned int a01[4] = {u01.x, u01.y, u01.z, u01.w};
            const unsigned int a10[4] = {u10.x, u10.y, u10.z, u10.w};
            const unsigned int a11[4] = {u11.x, u11.y, u11.z, u11.w};
            unsigned int pk[4];
            #pragma unroll
            for (int wd = 0; wd < 4; ++wd) {
                float slo = bf_lo(a00[wd]) * wt.x;
                slo = fmaf(bf_lo(a01[wd]), wt.y, slo);
                slo = fmaf(bf_lo(a10[wd]), wt.z, slo);
                slo = fmaf(bf_lo(a11[wd]), wt.w, slo);
                float shi = bf_hi(a00[wd]) * wt.x;
                shi = fmaf(bf_hi(a01[wd]), wt.y, shi);
                shi = fmaf(bf_hi(a10[wd]), wt.z, shi);
                shi = fmaf(bf_hi(a11[wd]), wt.w, shi);
                pk[wd] = pk2bf(slo, shi);
            }
            *(uint4*)&samp_s[dst + c8] = make_uint4(pk[0], pk[1], pk[2], pk[3]);
        }
    }
    __syncthreads();

    // ---- E: out[p][o] via MFMA; 1 bp load feeds 2 pixel halves
    {
        f32x4 acc0 = {0.f, 0.f, 0.f, 0.f};
        f32x4 acc1 = {0.f, 0.f, 0.f, 0.f};
        const unsigned short* bp = wB + ((size_t)(wave * 18) * 64 + lane) * 8;
        const int arow = (lane & 15) * ROWS + (lane >> 4) * 8;
        #pragma unroll
        for (int ks = 0; ks < 18; ++ks) {
            const int ro = arow + (ks >> 1) * KKS + (ks & 1) * 32;
            short8 av0 = *(const short8*)&samp_s[ro];
            short8 av1 = *(const short8*)&samp_s[ro + 16 * ROWS];
            short8 bv  = *(const short8*)bp;  bp += 512;
            acc0 = __builtin_amdgcn_mfma_f32_16x16x32_bf16(av0, bv, acc0, 0, 0, 0);
            acc1 = __builtin_amdgcn_mfma_f32_16x16x32_bf16(av1, bv, acc1, 0, 0, 0);
        }
        int o    = wave * 16 + (lane & 15);
        int prow = (lane >> 4) * 4;
        float* ob = out + (size_t)b * O_ * HW_ + (size_t)o * HW_ + ho * W_ + wo0;
        #pragma unroll
        for (int r = 0; r < 4; ++r) {
            ob[prow + r]      = acc0[r];
            ob[16 + prow + r] = acc1[r];
        }
    }
}

// ---------------- fallback: monolithic kernel (R11, verbatim; fp32 x_hwc) ----------------
__global__ __launch_bounds__(BDIM, 3) void dcn_mono(
    const float* __restrict__ xh,
    const float* __restrict__ b_off,
    const float* __restrict__ b_mod,
    const unsigned short* __restrict__ wB,
    const unsigned short* __restrict__ wO,
    float* __restrict__ out)
{
    __shared__ __align__(16) unsigned short samp_s[TP * ROWS];
    __shared__ __align__(16) float4 wtab[NE];
    __shared__ ushort4        itab[NE];
    __shared__ unsigned short dsttab[NE];

    float* offs = (float*)(samp_s + 8192);
    float* msk  = offs + TP * 18;

    const int t    = threadIdx.x;
    const int wave = t >> 6;
    const int lane = t & 63;
    const int blk  = ((blockIdx.x & 7) << 8) | (blockIdx.x >> 3);
    const int wo0  = (blk & 3) * TP;
    const int ho   = (blk >> 2) & 127;
    const int b    = blk >> 9;

    const float* xb = xh + (size_t)b * HW_ * C_;

    for (int u = t; u < 102 * 16; u += BDIM) {
        int row = u >> 4;
        int c4  = (u & 15) * 4;
        int ry  = row / XCOLS;
        int col = row - ry * XCOLS;
        int gy  = ho - 1 + ry;
        int gx  = wo0 - 1 + col;
        float4 v = make_float4(0.f, 0.f, 0.f, 0.f);
        if (gy >= 0 && gy < H_ && gx >= 0 && gx < W_)
            v = *(const float4*)&xb[(size_t)(gy * W_ + gx) * C_ + c4];
        *(uint2*)&samp_s[row * XTP + c4] = make_uint2(pk2bf(v.x, v.y), pk2bf(v.z, v.w));
    }
    __syncthreads();

    if (wave < 2) {
        f32x4 acc0 = {0.f, 0.f, 0.f, 0.f};
        f32x4 acc1 = {0.f, 0.f, 0.f, 0.f};
        const unsigned short* bp = wO + ((size_t)(wave * 18) * 64 + lane) * 8;
        const unsigned short* ap = samp_s + (lane & 15) * XTP + (lane >> 4) * 8;
        #pragma unroll
        for (int ks = 0; ks < 18; ++ks) {
            const int kk = ks >> 1, ky = kk / 3, kx = kk - ky * 3;
            const int ro = (ky * XCOLS + kx) * XTP + (ks & 1) * 32;
            short8 av0 = *(const short8*)&ap[ro];
            short8 av1 = *(const short8*)&ap[ro + 16 * XTP];
            short8 bv  = *(const short8*)bp;  bp += 512;
            acc0 = __builtin_amdgcn_mfma_f32_16x16x32_bf16(av0, bv, acc0, 0, 0, 0);
            acc1 = __builtin_amdgcn_mfma_f32_16x16x32_bf16(av1, bv, acc1, 0, 0, 0);
        }
        int oc   = wave * 16 + (lane & 15);
        int prow = (lane >> 4) * 4;
        if (oc < 18) {
            float bias = b_off[oc];
            #pragma unroll
            for (int r = 0; r < 4; ++r) {
                offs[(prow + r) * 18 + oc]      = acc0[r] + bias;
                offs[(prow + 16 + r) * 18 + oc] = acc1[r] + bias;
            }
        } else if (oc < 27) {
            int mc = oc - 18;
            float bias = b_mod[mc];
            #pragma unroll
            for (int r = 0; r < 4; ++r) {
                msk[(prow + r) * KK_ + mc]      = 2.f / (1.f + expf(-(acc0[r] + bias)));
                msk[(prow + 16 + r) * KK_ + mc] = 2.f / (1.f + expf(-(acc1[r] + bias)));
            }
        }
    }
    __syncthreads();

    for (int e = t; e < NE; e += BDIM) {
        int p  = e / 9;
        int kk = e - p * 9;
        int ky = kk / 3, kx = kk - ky * 3;
        float dy = offs[p * 18 + 2 * kk];
        float dx = offs[p * 18 + 2 * kk + 1];
        float py = dy + (float)(ho - 1 + ky);
        float px = dx + (float)(wo0 + p - 1 + kx);
        float y0f = floorf(py), x0f = floorf(px);
        float wy = py - y0f,    wx = px - x0f;
        int y0 = (int)y0f, x0 = (int)x0f;
        int y1 = y0 + 1,   x1 = x0 + 1;
        float m = msk[p * KK_ + kk];
        float vy0 = (y0 >= 0 && y0 < H_) ? 1.f : 0.f;
        float vy1 = (y1 >= 0 && y1 < H_) ? 1.f : 0.f;
        float vx0 = (x0 >= 0 && x0 < W_) ? 1.f : 0.f;
        float vx1 = (x1 >= 0 && x1 < W_) ? 1.f : 0.f;
        float4 wt;
        wt.x = (1.f - wy) * (1.f - wx) * m * vy0 * vx0;
        wt.y = (1.f - wy) * wx * m * vy0 * vx1;
        wt.z = wy * (1.f - wx) * m * vy1 * vx0;
        wt.w = wy * wx * m * vy1 * vx1;
        int yc0 = min(max(y0, 0), H_ - 1), yc1 = min(max(y1, 0), H_ - 1);
        int xc0 = min(max(x0, 0), W_ - 1), xc1 = min(max(x1, 0), W_ - 1);
        wtab[e] = wt;
        itab[e] = make_ushort4((unsigned short)(yc0 * W_ + xc0),
                               (unsigned short)(yc0 * W_ + xc1),
                               (unsigned short)(yc1 * W_ + xc0),
                               (unsigned short)(yc1 * W_ + xc1));
        dsttab[e] = (unsigned short)(p * ROWS + kk * KKS);
    }
    __syncthreads();

    {
        const int c4 = (lane & 15) * 4;
        const int q  = lane >> 4;
        const float* base = xb + c4;

        ushort4 ixr[18];
        #pragma unroll
        for (int it = 0; it < 18; ++it)
            ixr[it] = itab[wave * 72 + it * 4 + q];

        #define ISSUE(itv, d00, d01, d10, d11)                       \
            { ushort4 ix_ = ixr[itv];                                \
              d00 = *(const float4*)(base + ((size_t)ix_.x << 6));   \
              d01 = *(const float4*)(base + ((size_t)ix_.y << 6));   \
              d10 = *(const float4*)(base + ((size_t)ix_.z << 6));   \
              d11 = *(const float4*)(base + ((size_t)ix_.w << 6)); }

        float4 p00, p01, p10, p11;
        ISSUE(0, p00, p01, p10, p11);
        #pragma unroll
        for (int it = 0; it < 18; ++it) {
            float4 n00, n01, n10, n11;
            if (it < 17) ISSUE(it + 1, n00, n01, n10, n11);
            const int e = wave * 72 + it * 4 + q;
            float4 wt  = wtab[e];
            int    dst = dsttab[e];
            float s0 = p00.x * wt.x;
            s0 = fmaf(p01.x, wt.y, s0); s0 = fmaf(p10.x, wt.z, s0); s0 = fmaf(p11.x, wt.w, s0);
            float s1 = p00.y * wt.x;
            s1 = fmaf(p01.y, wt.y, s1); s1 = fmaf(p10.y, wt.z, s1); s1 = fmaf(p11.y, wt.w, s1);
            float s2 = p00.z * wt.x;
            s2 = fmaf(p01.z, wt.y, s2); s2 = fmaf(p10.z, wt.z, s2); s2 = fmaf(p11.z, wt.w, s2);
            float s3 = p00.w * wt.x;
            s3 = fmaf(p01.w, wt.y, s3); s3 = fmaf(p10.w, wt.z, s3); s3 = fmaf(p11.w, wt.w, s3);
            *(uint2*)&samp_s[dst + c4] = make_uint2(pk2bf(s0, s1), pk2bf(s2, s3));
            if (it < 17) { p00 = n00; p01 = n01; p10 = n10; p11 = n11; }
        }
        #undef ISSUE
    }
    __syncthreads();

    {
        f32x4 acc0 = {0.f, 0.f, 0.f, 0.f};
        f32x4 acc1 = {0.f, 0.f, 0.f, 0.f};
        const unsigned short* bp = wB + ((size_t)(wave * 18) * 64 + lane) * 8;
        const int arow = (lane & 15) * ROWS + (lane >> 4) * 8;
        #pragma unroll
        for (int ks = 0; ks < 18; ++ks) {
            const int ro = arow + (ks >> 1) * KKS + (ks & 1) * 32;
            short8 av0 = *(const short8*)&samp_s[ro];
            short8 av1 = *(const short8*)&samp_s[ro + 16 * ROWS];
            short8 bv  = *(const short8*)bp;  bp += 512;
            acc0 = __builtin_amdgcn_mfma_f32_16x16x32_bf16(av0, bv, acc0, 0, 0, 0);
            acc1 = __builtin_amdgcn_mfma_f32_16x16x32_bf16(av1, bv, acc1, 0, 0, 0);
        }
        int o    = wave * 16 + (lane & 15);
        int prow = (lane >> 4) * 4;
        float* ob = out + (size_t)b * O_ * HW_ + (size_t)o * HW_ + ho * W_ + wo0;
        #pragma unroll
        for (int r = 0; r < 4; ++r) {
            ob[prow + r]      = acc0[r];
            ob[16 + prow + r] = acc1[r];
        }
    }
}

extern "C" void kernel_launch(void* const* d_in, const int* in_sizes, int n_in,
                              void* d_out, int out_size, void* d_ws, size_t ws_size,
                              hipStream_t stream) {
    const float* x     = (const float*)d_in[0];
    const float* w_off = (const float*)d_in[1];
    const float* b_off = (const float*)d_in[2];
    const float* w_mod = (const float*)d_in[3];
    const float* b_mod = (const float*)d_in[4];
    const float* w_reg = (const float*)d_in[5];
    float* out = (float*)d_out;

    unsigned short* wpack = (unsigned short*)d_ws;

    if (ws_size >= WS_NEED) {
        float4*  wtab_g = (float4*)((char*)d_ws + WTAB_OFF);
        ushort4* itab_g = (ushort4*)((char*)d_ws + ITAB_OFF);
        unsigned short* x_hbf = (unsigned short*)((char*)d_ws + XHBF_OFF);
        dcn_pre<<<4096 + 216, BDIM, 0, stream>>>(x, (float*)x_hbf /*unused*/, x_hbf, 0,
                                                 w_off, w_mod, w_reg, wpack);
        dcn_tabs<<<NBLK, BDIM, 0, stream>>>(x_hbf, b_off, b_mod,
                                            wpack + 36864, wtab_g, itab_g);
        dcn_gather<<<NBLK, BDIM, 0, stream>>>(x_hbf, wtab_g, itab_g, wpack, out);
    } else {
        float* x_hwc = (float*)((char*)d_ws + XHWC_OFF);
        dcn_pre<<<4096 + 216, BDIM, 0, stream>>>(x, x_hwc, (unsigned short*)x_hwc /*unused*/, 1,
                                                 w_off, w_mod, w_reg, wpack);
        dcn_mono<<<NBLK, BDIM, 0, stream>>>(x_hwc, b_off, b_mod,
                                            wpack, wpack + 36864, out);
    }
}